// Round 5
// baseline (568.839 us; speedup 1.0000x reference)
//
#include <hip/hip_runtime.h>

// ---------------------------------------------------------------------------
// RGCN (basis decomposition, 2 layers) + mean-pool.
// Edge phase: relation-bucketed 16-edge tiles -> bf16 MFMA (16x16x32) ->
// LDS transpose -> plain full-line stores into dst-sorted msg buffer ->
// segmented sum (no atomics in the hot path). Counting sorts by relation
// (for tile uniformity) and by dst (for the segment sum).
//
// ws layout (bytes):
//   W1f     us[8*4096]  @ 0           W frags L1 (bf16)
//   W2f     us[8*1024]  @ 65536
//   xbf     us[N*64]    @ 81920       x in bf16
//   agg1    us[N*64]    @ 12881920    layer-1 agg (becomes h)
//   agg2    us[N*16]    @ 25681920    layer-2 agg
//   order   int[E+128]  @ 28881920    relation-sorted edge ids
//   wh      int[..]     @ 32882432    per-wave rel histograms
//   wbase   int[..]     @ 33013504
//   offs    int[16]     @ 33144576
//   start   int[..]     @ 33144640
//   deg     int[N]      @ 33145152
//   nodeoff int[N+1]    @ 33545152
//   cursor  int[N]      @ 33945280
//   btot    int[512]    @ 34345280
//   boff    int[512]    @ 34347328
//   dpos    int[E]      @ 34349376
//   msg     us[E*64]    @ 38349568    (layer-2 reuses: E*16)
// total need = 166,349,568 B; fallback to atomic path if ws smaller.
// ---------------------------------------------------------------------------

typedef __attribute__((ext_vector_type(8))) short bf16x8;
typedef __attribute__((ext_vector_type(4))) float f32x4;

#define WCHUNK 2048

__device__ __forceinline__ unsigned short f2bf(float f) {
    unsigned u = __float_as_uint(f);
    unsigned r = u + 0x7FFFu + ((u >> 16) & 1u);   // RNE
    return (unsigned short)(r >> 16);
}

__device__ __forceinline__ float bf2f(unsigned short u) {
    return __uint_as_float(((unsigned)u) << 16);
}

__device__ __forceinline__ float bcast(float v, int l) {
    return __uint_as_float(__builtin_amdgcn_readlane(__float_as_uint(v), l));
}

__device__ __forceinline__ void pkAddBf16(unsigned short* addr, unsigned pk) {
    asm volatile("global_atomic_pk_add_bf16 %0, %1, off"
                 :: "v"((unsigned long long)(size_t)addr), "v"(pk));
}

// ---- weights in B-fragment order (16x16x32 bf16): lane l holds
// B[k = kt*32+(l>>4)*8+j][n = nt*16+(l&15)], j=0..7
__global__ __launch_bounds__(256) void k_weights(
    const float* __restrict__ bases1, const float* __restrict__ coeff1,
    const float* __restrict__ bases2, const float* __restrict__ coeff2,
    unsigned short* __restrict__ W1f, unsigned short* __restrict__ W2f) {
    int r = blockIdx.x;
    int tid = threadIdx.x;
    float c1[8], c2[8];
#pragma unroll
    for (int b = 0; b < 8; ++b) { c1[b] = coeff1[r * 8 + b]; c2[b] = coeff2[r * 8 + b]; }
    for (int idx = tid; idx < 4096; idx += 256) {
        int j = idx & 7, lane = (idx >> 3) & 63, nt = (idx >> 9) & 3, kt = idx >> 11;
        int i = kt * 32 + ((lane >> 4) << 3) + j;
        int jo = nt * 16 + (lane & 15);
        float s = 0.f;
#pragma unroll
        for (int b = 0; b < 8; ++b) s = fmaf(c1[b], bases1[b * 4096 + i * 64 + jo], s);
        W1f[r * 4096 + idx] = f2bf(s);
    }
    for (int idx = tid; idx < 1024; idx += 256) {
        int j = idx & 7, lane = (idx >> 3) & 63, kt = idx >> 9;
        int i = kt * 32 + ((lane >> 4) << 3) + j;
        int jo = lane & 15;
        float s = 0.f;
#pragma unroll
        for (int b = 0; b < 8; ++b) s = fmaf(c2[b], bases2[b * 1024 + i * 16 + jo], s);
        W2f[r * 1024 + idx] = f2bf(s);
    }
}

__global__ __launch_bounds__(256) void k_xcast(
    const float* __restrict__ x, unsigned short* __restrict__ xbf, int n8) {
    int stride = gridDim.x * blockDim.x;
    for (int i = blockIdx.x * blockDim.x + threadIdx.x; i < n8; i += stride) {
        f32x4 u0 = *(const f32x4*)(x + (size_t)i * 8);
        f32x4 u1 = *(const f32x4*)(x + (size_t)i * 8 + 4);
        bf16x8 t;
        t[0] = (short)f2bf(u0[0]); t[1] = (short)f2bf(u0[1]);
        t[2] = (short)f2bf(u0[2]); t[3] = (short)f2bf(u0[3]);
        t[4] = (short)f2bf(u1[0]); t[5] = (short)f2bf(u1[1]);
        t[6] = (short)f2bf(u1[2]); t[7] = (short)f2bf(u1[3]);
        *(bf16x8*)(xbf + (size_t)i * 8) = t;
    }
}

// ---- relation counting sort (per-wave hist -> scan -> rank scatter)
__global__ __launch_bounds__(256) void k_whist(
    const int* __restrict__ et, int* __restrict__ wh, int nE, int nWaves) {
    int wid = (int)((blockIdx.x * blockDim.x + threadIdx.x) >> 6);
    int lane = threadIdx.x & 63;
    if (wid >= nWaves) return;
    int e0 = wid * WCHUNK, e1 = min(e0 + WCHUNK, nE);
    int c0 = 0, c1 = 0, c2 = 0, c3 = 0, c4 = 0, c5 = 0, c6 = 0, c7 = 0;
    for (int c = e0; c < e1; c += 64) {
        int e = c + lane;
        int r = (e < e1) ? et[e] : -1;
        c0 += __popcll(__ballot(r == 0)); c1 += __popcll(__ballot(r == 1));
        c2 += __popcll(__ballot(r == 2)); c3 += __popcll(__ballot(r == 3));
        c4 += __popcll(__ballot(r == 4)); c5 += __popcll(__ballot(r == 5));
        c6 += __popcll(__ballot(r == 6)); c7 += __popcll(__ballot(r == 7));
    }
    int v = c0;
    if (lane == 1) v = c1; if (lane == 2) v = c2; if (lane == 3) v = c3;
    if (lane == 4) v = c4; if (lane == 5) v = c5; if (lane == 6) v = c6;
    if (lane == 7) v = c7;
    if (lane < 8) wh[wid * 8 + lane] = v;
}

__global__ void k_scan2(const int* __restrict__ wh, int* __restrict__ wbase,
                        int* __restrict__ offs, int* __restrict__ order,
                        int nWaves) {
    __shared__ int tot[8];
    __shared__ int off[9];
    int r = threadIdx.x;
    if (r < 8) {
        int s = 0;
        for (int w = 0; w < nWaves; ++w) { wbase[w * 8 + r] = s; s += wh[w * 8 + r]; }
        tot[r] = s;
    }
    __syncthreads();
    if (r == 0) {
        int o = 0;
        for (int q = 0; q < 8; ++q) { off[q] = o; offs[q] = o; o += (tot[q] + 15) & ~15; }
        off[8] = o; offs[8] = o;
    }
    __syncthreads();
    if (r < 8) {
        int base = off[r];
        for (int w = 0; w < nWaves; ++w) wbase[w * 8 + r] += base;
        for (int p = base + tot[r]; p < off[r + 1]; ++p) order[p] = -1;
    }
}

__global__ __launch_bounds__(256) void k_scatter2(
    const int* __restrict__ et, const int* __restrict__ wbase,
    int* __restrict__ order, int nE, int nWaves) {
    int wid = (int)((blockIdx.x * blockDim.x + threadIdx.x) >> 6);
    int lane = threadIdx.x & 63;
    if (wid >= nWaves) return;
    int e0 = wid * WCHUNK, e1 = min(e0 + WCHUNK, nE);
    int cu0 = wbase[wid * 8 + 0], cu1 = wbase[wid * 8 + 1];
    int cu2 = wbase[wid * 8 + 2], cu3 = wbase[wid * 8 + 3];
    int cu4 = wbase[wid * 8 + 4], cu5 = wbase[wid * 8 + 5];
    int cu6 = wbase[wid * 8 + 6], cu7 = wbase[wid * 8 + 7];
    unsigned long long below = (1ull << lane) - 1ull;
    for (int c = e0; c < e1; c += 64) {
        int e = c + lane;
        int r = (e < e1) ? et[e] : -1;
        int pos = -1;
#define DOREL(RR, CU) { unsigned long long m = __ballot(r == RR); \
        if (r == RR) pos = CU + __popcll(m & below); CU += __popcll(m); }
        DOREL(0, cu0) DOREL(1, cu1) DOREL(2, cu2) DOREL(3, cu3)
        DOREL(4, cu4) DOREL(5, cu5) DOREL(6, cu6) DOREL(7, cu7)
#undef DOREL
        if (pos >= 0) order[pos] = e;
    }
}

// ---- dst counting sort: deg histogram -> block scan -> rank
__global__ __launch_bounds__(256) void k_zero(int* __restrict__ p, int n) {
    int i = blockIdx.x * blockDim.x + threadIdx.x;
    if (i < n) p[i] = 0;
}

__global__ __launch_bounds__(256) void k_histdst(
    const int* __restrict__ dst, int* __restrict__ deg, int nE) {
    int stride = gridDim.x * blockDim.x;
    for (int e = blockIdx.x * blockDim.x + threadIdx.x; e < nE; e += stride)
        atomicAdd(&deg[dst[e]], 1);
}

__global__ __launch_bounds__(256) void k_scanblk(
    const int* __restrict__ deg, int* __restrict__ nodeoff,
    int* __restrict__ btot, int nNodes) {
    __shared__ int sm[256];
    int tid = threadIdx.x;
    int n = blockIdx.x * 256 + tid;
    int d = (n < nNodes) ? deg[n] : 0;
    sm[tid] = d;
    __syncthreads();
#pragma unroll
    for (int off = 1; off < 256; off <<= 1) {
        int v = (tid >= off) ? sm[tid - off] : 0;
        __syncthreads();
        sm[tid] += v;
        __syncthreads();
    }
    if (n < nNodes) nodeoff[n] = sm[tid] - d;       // exclusive within block
    if (tid == 255) btot[blockIdx.x] = sm[255];
}

__global__ void k_scantop(const int* __restrict__ btot, int* __restrict__ boff, int nB) {
    __shared__ int sm[512];
    int t = threadIdx.x;
    int d = (t < nB) ? btot[t] : 0;
    sm[t] = d;
    __syncthreads();
#pragma unroll
    for (int off = 1; off < 512; off <<= 1) {
        int v = (t >= off) ? sm[t - off] : 0;
        __syncthreads();
        sm[t] += v;
        __syncthreads();
    }
    if (t < nB) boff[t] = sm[t] - d;                // exclusive
}

__global__ __launch_bounds__(256) void k_scanadd(
    int* __restrict__ nodeoff, const int* __restrict__ boff,
    int* __restrict__ cursor, int nNodes, int nE) {
    int n = blockIdx.x * 256 + threadIdx.x;
    if (n < nNodes) {
        int v = nodeoff[n] + boff[n >> 8];
        nodeoff[n] = v;
        cursor[n] = v;
    } else if (n == nNodes) {
        nodeoff[n] = nE;
    }
}

__global__ __launch_bounds__(256) void k_rank(
    const int* __restrict__ dst, int* __restrict__ cursor,
    int* __restrict__ dpos, int nE) {
    int stride = gridDim.x * blockDim.x;
    for (int e = blockIdx.x * blockDim.x + threadIdx.x; e < nE; e += stride)
        dpos[e] = atomicAdd(&cursor[dst[e]], 1);
}

// ---- self-loop layer1: agg1 = bf16(x @ wself1 + bias1)
__global__ __launch_bounds__(256) void k_lin1(
    const float* __restrict__ x, const float* __restrict__ wself,
    const float* __restrict__ bias, unsigned short* __restrict__ agg, int nNodes) {
    int lane = threadIdx.x & 63;
    int gw = (int)((blockIdx.x * blockDim.x + threadIdx.x) >> 6);
    int nW = (int)((gridDim.x * blockDim.x) >> 6);
    float w[64];
#pragma unroll
    for (int i = 0; i < 64; ++i) w[i] = wself[i * 64 + lane];
    float bj = bias[lane];
    for (int n = gw; n < nNodes; n += nW) {
        float xv = x[n * 64 + lane];
        float a0 = 0.f, a1 = 0.f, a2 = 0.f, a3 = 0.f;
#pragma unroll
        for (int i = 0; i < 64; i += 4) {
            a0 = fmaf(bcast(xv, i + 0), w[i + 0], a0);
            a1 = fmaf(bcast(xv, i + 1), w[i + 1], a1);
            a2 = fmaf(bcast(xv, i + 2), w[i + 2], a2);
            a3 = fmaf(bcast(xv, i + 3), w[i + 3], a3);
        }
        agg[(size_t)n * 64 + lane] = f2bf(bj + ((a0 + a1) + (a2 + a3)));
    }
}

// ---- edge GEMM layer1 -> msg rows (dst-sorted, plain full-line stores)
__global__ __launch_bounds__(256) void k_edgemm1(
    const unsigned short* __restrict__ xbf, const int* __restrict__ src,
    const int* __restrict__ order, const int* __restrict__ offs,
    const unsigned short* __restrict__ W1f, const int* __restrict__ dpos,
    unsigned short* __restrict__ msg) {
    __shared__ unsigned lds[4][16 * 36];
    int lane = threadIdx.x & 63;
    int wid = (int)(threadIdx.x >> 6);
    int tile = blockIdx.x * 4 + wid;
    int t16 = tile * 16;
    if (t16 >= offs[8]) return;
    int r = 0;
#pragma unroll
    for (int q = 1; q < 8; ++q) r += (t16 >= offs[q]);
    const unsigned short* Wf = W1f + r * 4096;
    bf16x8 b[2][4];
#pragma unroll
    for (int kt = 0; kt < 2; ++kt)
#pragma unroll
        for (int nt = 0; nt < 4; ++nt)
            b[kt][nt] = *(const bf16x8*)(Wf + (kt * 4 + nt) * 512 + lane * 8);
    int idxA = order[t16 + (lane & 15)];
    int sA = idxA >= 0 ? src[idxA] : 0;
    int dposA = idxA >= 0 ? dpos[idxA] : -1;
    const unsigned short* xrow = xbf + (size_t)sA * 64 + ((lane >> 4) << 3);
    bf16x8 a[2];
    a[0] = *(const bf16x8*)(xrow);
    a[1] = *(const bf16x8*)(xrow + 32);
    f32x4 z = {0.f, 0.f, 0.f, 0.f};
    f32x4 acc[4] = {z, z, z, z};
#pragma unroll
    for (int kt = 0; kt < 2; ++kt)
#pragma unroll
        for (int nt = 0; nt < 4; ++nt)
            acc[nt] = __builtin_amdgcn_mfma_f32_16x16x32_bf16(a[kt], b[kt][nt], acc[nt], 0, 0, 0);
    unsigned* L = lds[wid];
    const int even = !(lane & 1);
    const int cpair = (lane & 14) >> 1;
#pragma unroll
    for (int reg = 0; reg < 4; ++reg) {
        int row = ((lane >> 4) << 2) + reg;
#pragma unroll
        for (int nt = 0; nt < 4; ++nt) {
            float mine = acc[nt][reg];
            float oth = __shfl_xor(mine, 1, 64);
            unsigned pk = even ? ((unsigned)f2bf(mine) | ((unsigned)f2bf(oth) << 16))
                               : ((unsigned)f2bf(oth) | ((unsigned)f2bf(mine) << 16));
            if (even ? (nt < 2) : (nt >= 2)) L[row * 36 + cpair + nt * 8] = pk;
        }
    }
    // same-wave LDS RAW; compiler inserts lgkmcnt
    int row2 = lane >> 2, ch = lane & 3;
    int dposRow = __shfl(dposA, row2, 64);
    if (dposRow >= 0) {
        uint4 v0 = *(uint4*)&L[row2 * 36 + ch * 4];
        uint4 v1 = *(uint4*)&L[row2 * 36 + 16 + ch * 4];
        uint4* mp = (uint4*)(msg + (size_t)dposRow * 64);
        mp[ch] = v0;
        mp[4 + ch] = v1;
    }
}

// ---- segment sum layer1: agg1[n] += sum of msg rows [nodeoff[n],nodeoff[n+1])
__global__ __launch_bounds__(256) void k_seg1(
    const unsigned short* __restrict__ msg, const int* __restrict__ nodeoff,
    unsigned short* __restrict__ agg1, int nNodes) {
    int lane = threadIdx.x & 63;
    int gw = (int)((blockIdx.x * blockDim.x + threadIdx.x) >> 6);
    int nW = (int)((gridDim.x * blockDim.x) >> 6);
    for (int n = gw; n < nNodes; n += nW) {
        int s0 = nodeoff[n], s1 = nodeoff[n + 1];
        float acc = bf2f(agg1[(size_t)n * 64 + lane]);
        for (int rr = s0; rr < s1; ++rr) acc += bf2f(msg[(size_t)rr * 64 + lane]);
        agg1[(size_t)n * 64 + lane] = f2bf(acc);
    }
}

// ---- relu (in-place) + self-loop layer2 -> agg2 init
__global__ __launch_bounds__(256) void k_lin2(
    unsigned short* __restrict__ agg1, const float* __restrict__ wself,
    const float* __restrict__ bias, unsigned short* __restrict__ agg2, int nNodes) {
    int lane = threadIdx.x & 63;
    int j = lane & 15;
    int gw = (int)((blockIdx.x * blockDim.x + threadIdx.x) >> 6);
    int nW = (int)((gridDim.x * blockDim.x) >> 6);
    float w[64];
#pragma unroll
    for (int i = 0; i < 64; ++i) w[i] = wself[i * 16 + j];
    float bj = bias[j];
    for (int n = gw; n < nNodes; n += nW) {
        unsigned short raw = agg1[(size_t)n * 64 + lane];
        unsigned short rbf = (raw & 0x8000u) ? (unsigned short)0 : raw;
        agg1[(size_t)n * 64 + lane] = rbf;          // h in place
        float hv = bf2f(rbf);
        float a0 = 0.f, a1 = 0.f, a2 = 0.f, a3 = 0.f;
#pragma unroll
        for (int i = 0; i < 64; i += 4) {
            a0 = fmaf(bcast(hv, i + 0), w[i + 0], a0);
            a1 = fmaf(bcast(hv, i + 1), w[i + 1], a1);
            a2 = fmaf(bcast(hv, i + 2), w[i + 2], a2);
            a3 = fmaf(bcast(hv, i + 3), w[i + 3], a3);
        }
        if (lane < 16) agg2[(size_t)n * 16 + lane] = f2bf(bj + ((a0 + a1) + (a2 + a3)));
    }
}

// ---- edge GEMM layer2 -> msg rows (16 cols)
__global__ __launch_bounds__(256) void k_edgemm2(
    const unsigned short* __restrict__ h, const int* __restrict__ src,
    const int* __restrict__ order, const int* __restrict__ offs,
    const unsigned short* __restrict__ W2f, const int* __restrict__ dpos,
    unsigned short* __restrict__ msg) {
    __shared__ unsigned lds[4][16 * 12];
    int lane = threadIdx.x & 63;
    int wid = (int)(threadIdx.x >> 6);
    int tile = blockIdx.x * 4 + wid;
    int t16 = tile * 16;
    if (t16 >= offs[8]) return;
    int r = 0;
#pragma unroll
    for (int q = 1; q < 8; ++q) r += (t16 >= offs[q]);
    const unsigned short* Wf = W2f + r * 1024;
    bf16x8 b[2];
    b[0] = *(const bf16x8*)(Wf + lane * 8);
    b[1] = *(const bf16x8*)(Wf + 512 + lane * 8);
    int idxA = order[t16 + (lane & 15)];
    int sA = idxA >= 0 ? src[idxA] : 0;
    int dposA = idxA >= 0 ? dpos[idxA] : -1;
    const unsigned short* hrow = h + (size_t)sA * 64 + ((lane >> 4) << 3);
    bf16x8 a[2];
    a[0] = *(const bf16x8*)(hrow);
    a[1] = *(const bf16x8*)(hrow + 32);
    f32x4 acc = {0.f, 0.f, 0.f, 0.f};
    acc = __builtin_amdgcn_mfma_f32_16x16x32_bf16(a[0], b[0], acc, 0, 0, 0);
    acc = __builtin_amdgcn_mfma_f32_16x16x32_bf16(a[1], b[1], acc, 0, 0, 0);
    unsigned* L = lds[wid];
    const int even = !(lane & 1);
    const int cpair = (lane & 14) >> 1;
#pragma unroll
    for (int reg = 0; reg < 4; ++reg) {
        int row = ((lane >> 4) << 2) + reg;
        float mine = acc[reg];
        float oth = __shfl_xor(mine, 1, 64);
        unsigned pk = even ? ((unsigned)f2bf(mine) | ((unsigned)f2bf(oth) << 16))
                           : ((unsigned)f2bf(oth) | ((unsigned)f2bf(mine) << 16));
        if (even ? (reg < 2) : (reg >= 2)) L[row * 12 + cpair] = pk;
    }
    int row2 = lane >> 1, ch = lane & 1;
    int dposRow = (lane < 32) ? __shfl(dposA, row2, 64) : -1;
    if (lane < 32 && dposRow >= 0) {
        uint4 v = *(uint4*)&L[row2 * 12 + ch * 4];
        ((uint4*)(msg + (size_t)dposRow * 16))[ch] = v;
    }
}

// ---- segment sum layer2 (quarter-wave per node)
__global__ __launch_bounds__(256) void k_seg2(
    const unsigned short* __restrict__ msg, const int* __restrict__ nodeoff,
    unsigned short* __restrict__ agg2, int nNodes) {
    int c = threadIdx.x & 15;
    int gq = (int)((blockIdx.x * blockDim.x + threadIdx.x) >> 4);
    int nQ = (int)((gridDim.x * blockDim.x) >> 4);
    for (int n = gq; n < nNodes; n += nQ) {
        int s0 = nodeoff[n], s1 = nodeoff[n + 1];
        float acc = bf2f(agg2[(size_t)n * 16 + c]);
        for (int rr = s0; rr < s1; ++rr) acc += bf2f(msg[(size_t)rr * 16 + c]);
        agg2[(size_t)n * 16 + c] = f2bf(acc);
    }
}

// ---- fallback (atomic) edge kernels, used when ws is too small
__global__ __launch_bounds__(256) void k_edgemm1_at(
    const unsigned short* __restrict__ xbf, const int* __restrict__ src,
    const int* __restrict__ dst, const int* __restrict__ order,
    const int* __restrict__ offs, const unsigned short* __restrict__ W1f,
    unsigned short* __restrict__ agg) {
    int lane = threadIdx.x & 63;
    int wid = (int)(threadIdx.x >> 6);
    int tile = blockIdx.x * 4 + wid;
    int t16 = tile * 16;
    if (t16 >= offs[8]) return;
    int r = 0;
#pragma unroll
    for (int q = 1; q < 8; ++q) r += (t16 >= offs[q]);
    const unsigned short* Wf = W1f + r * 4096;
    bf16x8 b[2][4];
#pragma unroll
    for (int kt = 0; kt < 2; ++kt)
#pragma unroll
        for (int nt = 0; nt < 4; ++nt)
            b[kt][nt] = *(const bf16x8*)(Wf + (kt * 4 + nt) * 512 + lane * 8);
    int idxA = order[t16 + (lane & 15)];
    int sA = idxA >= 0 ? src[idxA] : 0;
    const unsigned short* xrow = xbf + (size_t)sA * 64 + ((lane >> 4) << 3);
    bf16x8 a[2];
    a[0] = *(const bf16x8*)(xrow);
    a[1] = *(const bf16x8*)(xrow + 32);
    f32x4 z = {0.f, 0.f, 0.f, 0.f};
    f32x4 acc[4] = {z, z, z, z};
#pragma unroll
    for (int kt = 0; kt < 2; ++kt)
#pragma unroll
        for (int nt = 0; nt < 4; ++nt)
            acc[nt] = __builtin_amdgcn_mfma_f32_16x16x32_bf16(a[kt], b[kt][nt], acc[nt], 0, 0, 0);
    const int even = !(lane & 1);
#pragma unroll
    for (int reg = 0; reg < 4; ++reg) {
        int row = ((lane >> 4) << 2) + reg;
        int idxD = order[t16 + row];
        if (idxD < 0) continue;
        int d = dst[idxD];
        unsigned short* ap = agg + (size_t)d * 64 + (lane & 14);
#pragma unroll
        for (int nt = 0; nt < 4; ++nt) {
            float mine = acc[nt][reg];
            float oth = __shfl_xor(mine, 1, 64);
            unsigned pk = even ? ((unsigned)f2bf(mine) | ((unsigned)f2bf(oth) << 16))
                               : ((unsigned)f2bf(oth) | ((unsigned)f2bf(mine) << 16));
            if (even ? (nt < 2) : (nt >= 2)) pkAddBf16(ap + nt * 16, pk);
        }
    }
}

__global__ __launch_bounds__(256) void k_edgemm2_at(
    const unsigned short* __restrict__ h, const int* __restrict__ src,
    const int* __restrict__ dst, const int* __restrict__ order,
    const int* __restrict__ offs, const unsigned short* __restrict__ W2f,
    unsigned short* __restrict__ agg2) {
    int lane = threadIdx.x & 63;
    int wid = (int)(threadIdx.x >> 6);
    int tile = blockIdx.x * 4 + wid;
    int t16 = tile * 16;
    if (t16 >= offs[8]) return;
    int r = 0;
#pragma unroll
    for (int q = 1; q < 8; ++q) r += (t16 >= offs[q]);
    const unsigned short* Wf = W2f + r * 1024;
    bf16x8 b[2];
    b[0] = *(const bf16x8*)(Wf + lane * 8);
    b[1] = *(const bf16x8*)(Wf + 512 + lane * 8);
    int idxA = order[t16 + (lane & 15)];
    int sA = idxA >= 0 ? src[idxA] : 0;
    const unsigned short* hrow = h + (size_t)sA * 64 + ((lane >> 4) << 3);
    bf16x8 a[2];
    a[0] = *(const bf16x8*)(hrow);
    a[1] = *(const bf16x8*)(hrow + 32);
    f32x4 acc = {0.f, 0.f, 0.f, 0.f};
    acc = __builtin_amdgcn_mfma_f32_16x16x32_bf16(a[0], b[0], acc, 0, 0, 0);
    acc = __builtin_amdgcn_mfma_f32_16x16x32_bf16(a[1], b[1], acc, 0, 0, 0);
    const int even = !(lane & 1);
#pragma unroll
    for (int reg = 0; reg < 4; ++reg) {
        int row = ((lane >> 4) << 2) + reg;
        int idxD = order[t16 + row];
        if (idxD < 0) continue;
        float mine = acc[reg];
        float oth = __shfl_xor(mine, 1, 64);
        int d = dst[idxD];
        unsigned pk = even ? ((unsigned)f2bf(mine) | ((unsigned)f2bf(oth) << 16))
                           : ((unsigned)f2bf(oth) | ((unsigned)f2bf(mine) << 16));
        if (even ? (reg < 2) : (reg >= 2))
            pkAddBf16(agg2 + (size_t)d * 16 + (lane & 14), pk);
    }
}

__global__ void k_bounds(const int* __restrict__ gid, int* __restrict__ start, int nNodes) {
    int t = blockIdx.x * blockDim.x + threadIdx.x;
    if (t > 64) return;
    int lo = 0, hi = nNodes;
    while (lo < hi) {
        int mid = (lo + hi) >> 1;
        if (gid[mid] < t) lo = mid + 1; else hi = mid;
    }
    start[t] = lo;
}

__global__ __launch_bounds__(256) void k_pool(
    const unsigned short* __restrict__ agg2, const int* __restrict__ start,
    float* __restrict__ out) {
    __shared__ float sm[256];
    int g = blockIdx.x;
    int t = threadIdx.x;
    int c = t & 15, idx = t >> 4;
    int s0 = start[g], s1 = start[g + 1];
    float acc = 0.f;
    for (int n = s0 + idx; n < s1; n += 16) acc += fmaxf(bf2f(agg2[(size_t)n * 16 + c]), 0.f);
    sm[t] = acc;
    __syncthreads();
#pragma unroll
    for (int off = 128; off >= 16; off >>= 1) {
        if (t < off) sm[t] += sm[t + off];
        __syncthreads();
    }
    if (t < 16) {
        float cnt = (float)(s1 - s0);
        out[g * 16 + t] = sm[t] / fmaxf(cnt, 1.f);
    }
}

extern "C" void kernel_launch(void* const* d_in, const int* in_sizes, int n_in,
                              void* d_out, int out_size, void* d_ws, size_t ws_size,
                              hipStream_t stream) {
    const float* x      = (const float*)d_in[0];
    const int*   src    = (const int*)d_in[1];
    const int*   dst    = (const int*)d_in[2];
    const int*   et     = (const int*)d_in[3];
    const int*   gid    = (const int*)d_in[4];
    const float* bases1 = (const float*)d_in[5];
    const float* coeff1 = (const float*)d_in[6];
    const float* wself1 = (const float*)d_in[7];
    const float* bias1  = (const float*)d_in[8];
    const float* bases2 = (const float*)d_in[9];
    const float* coeff2 = (const float*)d_in[10];
    const float* wself2 = (const float*)d_in[11];
    const float* bias2  = (const float*)d_in[12];
    float* out = (float*)d_out;

    int nNodes = in_sizes[0] / 64;
    int nE = in_sizes[1];

    char* ws = (char*)d_ws;
    unsigned short* W1f  = (unsigned short*)(ws);
    unsigned short* W2f  = (unsigned short*)(ws + 65536);
    unsigned short* xbf  = (unsigned short*)(ws + 81920);
    unsigned short* agg1 = (unsigned short*)(ws + 12881920);
    unsigned short* agg2 = (unsigned short*)(ws + 25681920);
    int*   order   = (int*)(ws + 28881920);
    int*   wh      = (int*)(ws + 32882432);
    int*   wbase   = (int*)(ws + 33013504);
    int*   offs    = (int*)(ws + 33144576);
    int*   start   = (int*)(ws + 33144640);
    int*   deg     = (int*)(ws + 33145152);
    int*   nodeoff = (int*)(ws + 33545152);
    int*   cursor  = (int*)(ws + 33945280);
    int*   btot    = (int*)(ws + 34345280);
    int*   boff    = (int*)(ws + 34347328);
    int*   dpos    = (int*)(ws + 34349376);
    unsigned short* msg = (unsigned short*)(ws + 38349568);
    const size_t NEED = 38349568ull + (size_t)nE * 64 * 2;
    bool big = ws_size >= NEED;

    int nWaves = (nE + WCHUNK - 1) / WCHUNK;
    int hb = (nWaves * 64 + 255) / 256;
    int tiles = (nE + 128) / 16;
    int eb = (tiles + 3) / 4;
    int nB = (nNodes + 255) / 256;

    hipLaunchKernelGGL(k_weights, dim3(8), dim3(256), 0, stream,
                       bases1, coeff1, bases2, coeff2, W1f, W2f);
    hipLaunchKernelGGL(k_xcast, dim3(2048), dim3(256), 0, stream,
                       x, xbf, nNodes * 8);
    hipLaunchKernelGGL(k_whist, dim3(hb), dim3(256), 0, stream, et, wh, nE, nWaves);
    hipLaunchKernelGGL(k_scan2, dim3(1), dim3(64), 0, stream,
                       wh, wbase, offs, order, nWaves);
    hipLaunchKernelGGL(k_scatter2, dim3(hb), dim3(256), 0, stream,
                       et, wbase, order, nE, nWaves);
    hipLaunchKernelGGL(k_lin1, dim3(512), dim3(256), 0, stream,
                       x, wself1, bias1, agg1, nNodes);
    if (big) {
        hipLaunchKernelGGL(k_zero, dim3(nB), dim3(256), 0, stream, deg, nNodes);
        hipLaunchKernelGGL(k_histdst, dim3(1024), dim3(256), 0, stream, dst, deg, nE);
        hipLaunchKernelGGL(k_scanblk, dim3(nB), dim3(256), 0, stream,
                           deg, nodeoff, btot, nNodes);
        hipLaunchKernelGGL(k_scantop, dim3(1), dim3(512), 0, stream, btot, boff, nB);
        hipLaunchKernelGGL(k_scanadd, dim3(nB + 1), dim3(256), 0, stream,
                           nodeoff, boff, cursor, nNodes, nE);
        hipLaunchKernelGGL(k_rank, dim3(1024), dim3(256), 0, stream,
                           dst, cursor, dpos, nE);
        hipLaunchKernelGGL(k_edgemm1, dim3(eb), dim3(256), 0, stream,
                           xbf, src, order, offs, W1f, dpos, msg);
        hipLaunchKernelGGL(k_seg1, dim3(1024), dim3(256), 0, stream,
                           msg, nodeoff, agg1, nNodes);
        hipLaunchKernelGGL(k_lin2, dim3(512), dim3(256), 0, stream,
                           agg1, wself2, bias2, agg2, nNodes);
        hipLaunchKernelGGL(k_edgemm2, dim3(eb), dim3(256), 0, stream,
                           agg1, src, order, offs, W2f, dpos, msg);
        hipLaunchKernelGGL(k_seg2, dim3(512), dim3(256), 0, stream,
                           msg, nodeoff, agg2, nNodes);
    } else {
        hipLaunchKernelGGL(k_edgemm1_at, dim3(eb), dim3(256), 0, stream,
                           xbf, src, dst, order, offs, W1f, agg1);
        hipLaunchKernelGGL(k_lin2, dim3(512), dim3(256), 0, stream,
                           agg1, wself2, bias2, agg2, nNodes);
        hipLaunchKernelGGL(k_edgemm2_at, dim3(eb), dim3(256), 0, stream,
                           agg1, src, dst, order, offs, W2f, agg2);
    }
    hipLaunchKernelGGL(k_bounds, dim3(1), dim3(128), 0, stream, gid, start, nNodes);
    hipLaunchKernelGGL(k_pool, dim3(64), dim3(256), 0, stream, agg2, start, out);
}

// Round 6
// 483.185 us; speedup vs baseline: 1.1773x; 1.1773x over previous
//
#include <hip/hip_runtime.h>

// ---------------------------------------------------------------------------
// RGCN (basis decomposition, 2 layers) + mean-pool.
// Edge phase: relation-bucketed 16-edge tiles -> bf16 MFMA (16x16x32) ->
// LDS transpose -> plain full-line stores into dst-sorted msg buffer ->
// segmented sum (no atomics in the hot path). Counting sorts by relation
// (for tile uniformity) and by dst (for the segment sum).
// Round 6: k_scan2 parallelized (one wave per relation, shfl_up scan) —
// was 107us of serial latency, now ~3us.
//
// ws layout (bytes):
//   W1f     us[8*4096]  @ 0           W frags L1 (bf16)
//   W2f     us[8*1024]  @ 65536
//   xbf     us[N*64]    @ 81920       x in bf16
//   agg1    us[N*64]    @ 12881920    layer-1 agg (becomes h)
//   agg2    us[N*16]    @ 25681920    layer-2 agg
//   order   int[E+128]  @ 28881920    relation-sorted edge ids
//   wh      int[..]     @ 32882432    per-wave rel histograms
//   wbase   int[..]     @ 33013504
//   offs    int[16]     @ 33144576
//   start   int[..]     @ 33144640
//   deg     int[N]      @ 33145152
//   nodeoff int[N+1]    @ 33545152
//   cursor  int[N]      @ 33945280
//   btot    int[512]    @ 34345280
//   boff    int[512]    @ 34347328
//   dpos    int[E]      @ 34349376
//   msg     us[E*64]    @ 38349568    (layer-2 reuses: E*16)
// total need = 166,349,568 B; fallback to atomic path if ws smaller.
// ---------------------------------------------------------------------------

typedef __attribute__((ext_vector_type(8))) short bf16x8;
typedef __attribute__((ext_vector_type(4))) float f32x4;

#define WCHUNK 2048

__device__ __forceinline__ unsigned short f2bf(float f) {
    unsigned u = __float_as_uint(f);
    unsigned r = u + 0x7FFFu + ((u >> 16) & 1u);   // RNE
    return (unsigned short)(r >> 16);
}

__device__ __forceinline__ float bf2f(unsigned short u) {
    return __uint_as_float(((unsigned)u) << 16);
}

__device__ __forceinline__ float bcast(float v, int l) {
    return __uint_as_float(__builtin_amdgcn_readlane(__float_as_uint(v), l));
}

__device__ __forceinline__ void pkAddBf16(unsigned short* addr, unsigned pk) {
    asm volatile("global_atomic_pk_add_bf16 %0, %1, off"
                 :: "v"((unsigned long long)(size_t)addr), "v"(pk));
}

// ---- weights in B-fragment order (16x16x32 bf16): lane l holds
// B[k = kt*32+(l>>4)*8+j][n = nt*16+(l&15)], j=0..7
__global__ __launch_bounds__(256) void k_weights(
    const float* __restrict__ bases1, const float* __restrict__ coeff1,
    const float* __restrict__ bases2, const float* __restrict__ coeff2,
    unsigned short* __restrict__ W1f, unsigned short* __restrict__ W2f) {
    int r = blockIdx.x;
    int tid = threadIdx.x;
    float c1[8], c2[8];
#pragma unroll
    for (int b = 0; b < 8; ++b) { c1[b] = coeff1[r * 8 + b]; c2[b] = coeff2[r * 8 + b]; }
    for (int idx = tid; idx < 4096; idx += 256) {
        int j = idx & 7, lane = (idx >> 3) & 63, nt = (idx >> 9) & 3, kt = idx >> 11;
        int i = kt * 32 + ((lane >> 4) << 3) + j;
        int jo = nt * 16 + (lane & 15);
        float s = 0.f;
#pragma unroll
        for (int b = 0; b < 8; ++b) s = fmaf(c1[b], bases1[b * 4096 + i * 64 + jo], s);
        W1f[r * 4096 + idx] = f2bf(s);
    }
    for (int idx = tid; idx < 1024; idx += 256) {
        int j = idx & 7, lane = (idx >> 3) & 63, kt = idx >> 9;
        int i = kt * 32 + ((lane >> 4) << 3) + j;
        int jo = lane & 15;
        float s = 0.f;
#pragma unroll
        for (int b = 0; b < 8; ++b) s = fmaf(c2[b], bases2[b * 1024 + i * 16 + jo], s);
        W2f[r * 1024 + idx] = f2bf(s);
    }
}

__global__ __launch_bounds__(256) void k_xcast(
    const float* __restrict__ x, unsigned short* __restrict__ xbf, int n8) {
    int stride = gridDim.x * blockDim.x;
    for (int i = blockIdx.x * blockDim.x + threadIdx.x; i < n8; i += stride) {
        f32x4 u0 = *(const f32x4*)(x + (size_t)i * 8);
        f32x4 u1 = *(const f32x4*)(x + (size_t)i * 8 + 4);
        bf16x8 t;
        t[0] = (short)f2bf(u0[0]); t[1] = (short)f2bf(u0[1]);
        t[2] = (short)f2bf(u0[2]); t[3] = (short)f2bf(u0[3]);
        t[4] = (short)f2bf(u1[0]); t[5] = (short)f2bf(u1[1]);
        t[6] = (short)f2bf(u1[2]); t[7] = (short)f2bf(u1[3]);
        *(bf16x8*)(xbf + (size_t)i * 8) = t;
    }
}

// ---- relation counting sort (per-wave hist -> scan -> rank scatter)
__global__ __launch_bounds__(256) void k_whist(
    const int* __restrict__ et, int* __restrict__ wh, int nE, int nWaves) {
    int wid = (int)((blockIdx.x * blockDim.x + threadIdx.x) >> 6);
    int lane = threadIdx.x & 63;
    if (wid >= nWaves) return;
    int e0 = wid * WCHUNK, e1 = min(e0 + WCHUNK, nE);
    int c0 = 0, c1 = 0, c2 = 0, c3 = 0, c4 = 0, c5 = 0, c6 = 0, c7 = 0;
    for (int c = e0; c < e1; c += 64) {
        int e = c + lane;
        int r = (e < e1) ? et[e] : -1;
        c0 += __popcll(__ballot(r == 0)); c1 += __popcll(__ballot(r == 1));
        c2 += __popcll(__ballot(r == 2)); c3 += __popcll(__ballot(r == 3));
        c4 += __popcll(__ballot(r == 4)); c5 += __popcll(__ballot(r == 5));
        c6 += __popcll(__ballot(r == 6)); c7 += __popcll(__ballot(r == 7));
    }
    int v = c0;
    if (lane == 1) v = c1; if (lane == 2) v = c2; if (lane == 3) v = c3;
    if (lane == 4) v = c4; if (lane == 5) v = c5; if (lane == 6) v = c6;
    if (lane == 7) v = c7;
    if (lane < 8) wh[wid * 8 + lane] = v;
}

// ---- parallel scan: one wave per relation; chunked shfl_up scan with carry
__global__ __launch_bounds__(512) void k_scan2(
    const int* __restrict__ wh, int* __restrict__ wbase,
    int* __restrict__ offs, int* __restrict__ order, int nWaves) {
    __shared__ int tot[8];
    __shared__ int off[9];
    int rel = (int)(threadIdx.x >> 6);   // 0..7
    int lane = (int)(threadIdx.x & 63);
    int carry = 0;
    for (int c = 0; c < nWaves; c += 64) {
        int w = c + lane;
        int v = (w < nWaves) ? wh[w * 8 + rel] : 0;
        int s = v;
#pragma unroll
        for (int d = 1; d < 64; d <<= 1) {
            int t = __shfl_up(s, d, 64);
            if (lane >= d) s += t;
        }
        if (w < nWaves) wbase[w * 8 + rel] = carry + s - v;   // exclusive
        carry += __shfl(s, 63, 64);
    }
    if (lane == 0) tot[rel] = carry;
    __syncthreads();
    if (threadIdx.x == 0) {
        int o = 0;
        for (int q = 0; q < 8; ++q) { off[q] = o; offs[q] = o; o += (tot[q] + 15) & ~15; }
        off[8] = o; offs[8] = o;
    }
    __syncthreads();
    int base = off[rel];
    for (int w = lane; w < nWaves; w += 64) wbase[w * 8 + rel] += base;
    for (int p = base + tot[rel] + lane; p < off[rel + 1]; p += 64) order[p] = -1;
}

__global__ __launch_bounds__(256) void k_scatter2(
    const int* __restrict__ et, const int* __restrict__ wbase,
    int* __restrict__ order, int nE, int nWaves) {
    int wid = (int)((blockIdx.x * blockDim.x + threadIdx.x) >> 6);
    int lane = threadIdx.x & 63;
    if (wid >= nWaves) return;
    int e0 = wid * WCHUNK, e1 = min(e0 + WCHUNK, nE);
    int cu0 = wbase[wid * 8 + 0], cu1 = wbase[wid * 8 + 1];
    int cu2 = wbase[wid * 8 + 2], cu3 = wbase[wid * 8 + 3];
    int cu4 = wbase[wid * 8 + 4], cu5 = wbase[wid * 8 + 5];
    int cu6 = wbase[wid * 8 + 6], cu7 = wbase[wid * 8 + 7];
    unsigned long long below = (1ull << lane) - 1ull;
    for (int c = e0; c < e1; c += 64) {
        int e = c + lane;
        int r = (e < e1) ? et[e] : -1;
        int pos = -1;
#define DOREL(RR, CU) { unsigned long long m = __ballot(r == RR); \
        if (r == RR) pos = CU + __popcll(m & below); CU += __popcll(m); }
        DOREL(0, cu0) DOREL(1, cu1) DOREL(2, cu2) DOREL(3, cu3)
        DOREL(4, cu4) DOREL(5, cu5) DOREL(6, cu6) DOREL(7, cu7)
#undef DOREL
        if (pos >= 0) order[pos] = e;
    }
}

// ---- dst counting sort: deg histogram -> block scan -> rank
__global__ __launch_bounds__(256) void k_zero(int* __restrict__ p, int n) {
    int i = blockIdx.x * blockDim.x + threadIdx.x;
    if (i < n) p[i] = 0;
}

__global__ __launch_bounds__(256) void k_histdst(
    const int* __restrict__ dst, int* __restrict__ deg, int nE) {
    int stride = gridDim.x * blockDim.x;
    for (int e = blockIdx.x * blockDim.x + threadIdx.x; e < nE; e += stride)
        atomicAdd(&deg[dst[e]], 1);
}

__global__ __launch_bounds__(256) void k_scanblk(
    const int* __restrict__ deg, int* __restrict__ nodeoff,
    int* __restrict__ btot, int nNodes) {
    __shared__ int sm[256];
    int tid = threadIdx.x;
    int n = blockIdx.x * 256 + tid;
    int d = (n < nNodes) ? deg[n] : 0;
    sm[tid] = d;
    __syncthreads();
#pragma unroll
    for (int off = 1; off < 256; off <<= 1) {
        int v = (tid >= off) ? sm[tid - off] : 0;
        __syncthreads();
        sm[tid] += v;
        __syncthreads();
    }
    if (n < nNodes) nodeoff[n] = sm[tid] - d;       // exclusive within block
    if (tid == 255) btot[blockIdx.x] = sm[255];
}

__global__ void k_scantop(const int* __restrict__ btot, int* __restrict__ boff, int nB) {
    __shared__ int sm[512];
    int t = threadIdx.x;
    int d = (t < nB) ? btot[t] : 0;
    sm[t] = d;
    __syncthreads();
#pragma unroll
    for (int off = 1; off < 512; off <<= 1) {
        int v = (t >= off) ? sm[t - off] : 0;
        __syncthreads();
        sm[t] += v;
        __syncthreads();
    }
    if (t < nB) boff[t] = sm[t] - d;                // exclusive
}

__global__ __launch_bounds__(256) void k_scanadd(
    int* __restrict__ nodeoff, const int* __restrict__ boff,
    int* __restrict__ cursor, int nNodes, int nE) {
    int n = blockIdx.x * 256 + threadIdx.x;
    if (n < nNodes) {
        int v = nodeoff[n] + boff[n >> 8];
        nodeoff[n] = v;
        cursor[n] = v;
    } else if (n == nNodes) {
        nodeoff[n] = nE;
    }
}

__global__ __launch_bounds__(256) void k_rank(
    const int* __restrict__ dst, int* __restrict__ cursor,
    int* __restrict__ dpos, int nE) {
    int stride = gridDim.x * blockDim.x;
    for (int e = blockIdx.x * blockDim.x + threadIdx.x; e < nE; e += stride)
        dpos[e] = atomicAdd(&cursor[dst[e]], 1);
}

// ---- self-loop layer1: agg1 = bf16(x @ wself1 + bias1)
__global__ __launch_bounds__(256) void k_lin1(
    const float* __restrict__ x, const float* __restrict__ wself,
    const float* __restrict__ bias, unsigned short* __restrict__ agg, int nNodes) {
    int lane = threadIdx.x & 63;
    int gw = (int)((blockIdx.x * blockDim.x + threadIdx.x) >> 6);
    int nW = (int)((gridDim.x * blockDim.x) >> 6);
    float w[64];
#pragma unroll
    for (int i = 0; i < 64; ++i) w[i] = wself[i * 64 + lane];
    float bj = bias[lane];
    for (int n = gw; n < nNodes; n += nW) {
        float xv = x[n * 64 + lane];
        float a0 = 0.f, a1 = 0.f, a2 = 0.f, a3 = 0.f;
#pragma unroll
        for (int i = 0; i < 64; i += 4) {
            a0 = fmaf(bcast(xv, i + 0), w[i + 0], a0);
            a1 = fmaf(bcast(xv, i + 1), w[i + 1], a1);
            a2 = fmaf(bcast(xv, i + 2), w[i + 2], a2);
            a3 = fmaf(bcast(xv, i + 3), w[i + 3], a3);
        }
        agg[(size_t)n * 64 + lane] = f2bf(bj + ((a0 + a1) + (a2 + a3)));
    }
}

// ---- edge GEMM layer1 -> msg rows (dst-sorted, plain full-line stores)
__global__ __launch_bounds__(256) void k_edgemm1(
    const unsigned short* __restrict__ xbf, const int* __restrict__ src,
    const int* __restrict__ order, const int* __restrict__ offs,
    const unsigned short* __restrict__ W1f, const int* __restrict__ dpos,
    unsigned short* __restrict__ msg) {
    __shared__ unsigned lds[4][16 * 36];
    int lane = threadIdx.x & 63;
    int wid = (int)(threadIdx.x >> 6);
    int tile = blockIdx.x * 4 + wid;
    int t16 = tile * 16;
    if (t16 >= offs[8]) return;
    int r = 0;
#pragma unroll
    for (int q = 1; q < 8; ++q) r += (t16 >= offs[q]);
    const unsigned short* Wf = W1f + r * 4096;
    bf16x8 b[2][4];
#pragma unroll
    for (int kt = 0; kt < 2; ++kt)
#pragma unroll
        for (int nt = 0; nt < 4; ++nt)
            b[kt][nt] = *(const bf16x8*)(Wf + (kt * 4 + nt) * 512 + lane * 8);
    int idxA = order[t16 + (lane & 15)];
    int sA = idxA >= 0 ? src[idxA] : 0;
    int dposA = idxA >= 0 ? dpos[idxA] : -1;
    const unsigned short* xrow = xbf + (size_t)sA * 64 + ((lane >> 4) << 3);
    bf16x8 a[2];
    a[0] = *(const bf16x8*)(xrow);
    a[1] = *(const bf16x8*)(xrow + 32);
    f32x4 z = {0.f, 0.f, 0.f, 0.f};
    f32x4 acc[4] = {z, z, z, z};
#pragma unroll
    for (int kt = 0; kt < 2; ++kt)
#pragma unroll
        for (int nt = 0; nt < 4; ++nt)
            acc[nt] = __builtin_amdgcn_mfma_f32_16x16x32_bf16(a[kt], b[kt][nt], acc[nt], 0, 0, 0);
    unsigned* L = lds[wid];
    const int even = !(lane & 1);
    const int cpair = (lane & 14) >> 1;
#pragma unroll
    for (int reg = 0; reg < 4; ++reg) {
        int row = ((lane >> 4) << 2) + reg;
#pragma unroll
        for (int nt = 0; nt < 4; ++nt) {
            float mine = acc[nt][reg];
            float oth = __shfl_xor(mine, 1, 64);
            unsigned pk = even ? ((unsigned)f2bf(mine) | ((unsigned)f2bf(oth) << 16))
                               : ((unsigned)f2bf(oth) | ((unsigned)f2bf(mine) << 16));
            if (even ? (nt < 2) : (nt >= 2)) L[row * 36 + cpair + nt * 8] = pk;
        }
    }
    // same-wave LDS RAW; compiler inserts lgkmcnt
    int row2 = lane >> 2, ch = lane & 3;
    int dposRow = __shfl(dposA, row2, 64);
    if (dposRow >= 0) {
        uint4 v0 = *(uint4*)&L[row2 * 36 + ch * 4];
        uint4 v1 = *(uint4*)&L[row2 * 36 + 16 + ch * 4];
        uint4* mp = (uint4*)(msg + (size_t)dposRow * 64);
        mp[ch] = v0;
        mp[4 + ch] = v1;
    }
}

// ---- segment sum layer1: agg1[n] += sum of msg rows [nodeoff[n],nodeoff[n+1])
__global__ __launch_bounds__(256) void k_seg1(
    const unsigned short* __restrict__ msg, const int* __restrict__ nodeoff,
    unsigned short* __restrict__ agg1, int nNodes) {
    int lane = threadIdx.x & 63;
    int gw = (int)((blockIdx.x * blockDim.x + threadIdx.x) >> 6);
    int nW = (int)((gridDim.x * blockDim.x) >> 6);
    for (int n = gw; n < nNodes; n += nW) {
        int s0 = nodeoff[n], s1 = nodeoff[n + 1];
        float acc = bf2f(agg1[(size_t)n * 64 + lane]);
        for (int rr = s0; rr < s1; ++rr) acc += bf2f(msg[(size_t)rr * 64 + lane]);
        agg1[(size_t)n * 64 + lane] = f2bf(acc);
    }
}

// ---- relu (in-place) + self-loop layer2 -> agg2 init
__global__ __launch_bounds__(256) void k_lin2(
    unsigned short* __restrict__ agg1, const float* __restrict__ wself,
    const float* __restrict__ bias, unsigned short* __restrict__ agg2, int nNodes) {
    int lane = threadIdx.x & 63;
    int j = lane & 15;
    int gw = (int)((blockIdx.x * blockDim.x + threadIdx.x) >> 6);
    int nW = (int)((gridDim.x * blockDim.x) >> 6);
    float w[64];
#pragma unroll
    for (int i = 0; i < 64; ++i) w[i] = wself[i * 16 + j];
    float bj = bias[j];
    for (int n = gw; n < nNodes; n += nW) {
        unsigned short raw = agg1[(size_t)n * 64 + lane];
        unsigned short rbf = (raw & 0x8000u) ? (unsigned short)0 : raw;
        agg1[(size_t)n * 64 + lane] = rbf;          // h in place
        float hv = bf2f(rbf);
        float a0 = 0.f, a1 = 0.f, a2 = 0.f, a3 = 0.f;
#pragma unroll
        for (int i = 0; i < 64; i += 4) {
            a0 = fmaf(bcast(hv, i + 0), w[i + 0], a0);
            a1 = fmaf(bcast(hv, i + 1), w[i + 1], a1);
            a2 = fmaf(bcast(hv, i + 2), w[i + 2], a2);
            a3 = fmaf(bcast(hv, i + 3), w[i + 3], a3);
        }
        if (lane < 16) agg2[(size_t)n * 16 + lane] = f2bf(bj + ((a0 + a1) + (a2 + a3)));
    }
}

// ---- edge GEMM layer2 -> msg rows (16 cols)
__global__ __launch_bounds__(256) void k_edgemm2(
    const unsigned short* __restrict__ h, const int* __restrict__ src,
    const int* __restrict__ order, const int* __restrict__ offs,
    const unsigned short* __restrict__ W2f, const int* __restrict__ dpos,
    unsigned short* __restrict__ msg) {
    __shared__ unsigned lds[4][16 * 12];
    int lane = threadIdx.x & 63;
    int wid = (int)(threadIdx.x >> 6);
    int tile = blockIdx.x * 4 + wid;
    int t16 = tile * 16;
    if (t16 >= offs[8]) return;
    int r = 0;
#pragma unroll
    for (int q = 1; q < 8; ++q) r += (t16 >= offs[q]);
    const unsigned short* Wf = W2f + r * 1024;
    bf16x8 b[2];
    b[0] = *(const bf16x8*)(Wf + lane * 8);
    b[1] = *(const bf16x8*)(Wf + 512 + lane * 8);
    int idxA = order[t16 + (lane & 15)];
    int sA = idxA >= 0 ? src[idxA] : 0;
    int dposA = idxA >= 0 ? dpos[idxA] : -1;
    const unsigned short* hrow = h + (size_t)sA * 64 + ((lane >> 4) << 3);
    bf16x8 a[2];
    a[0] = *(const bf16x8*)(hrow);
    a[1] = *(const bf16x8*)(hrow + 32);
    f32x4 acc = {0.f, 0.f, 0.f, 0.f};
    acc = __builtin_amdgcn_mfma_f32_16x16x32_bf16(a[0], b[0], acc, 0, 0, 0);
    acc = __builtin_amdgcn_mfma_f32_16x16x32_bf16(a[1], b[1], acc, 0, 0, 0);
    unsigned* L = lds[wid];
    const int even = !(lane & 1);
    const int cpair = (lane & 14) >> 1;
#pragma unroll
    for (int reg = 0; reg < 4; ++reg) {
        int row = ((lane >> 4) << 2) + reg;
        float mine = acc[reg];
        float oth = __shfl_xor(mine, 1, 64);
        unsigned pk = even ? ((unsigned)f2bf(mine) | ((unsigned)f2bf(oth) << 16))
                           : ((unsigned)f2bf(oth) | ((unsigned)f2bf(mine) << 16));
        if (even ? (reg < 2) : (reg >= 2)) L[row * 12 + cpair] = pk;
    }
    int row2 = lane >> 1, ch = lane & 1;
    int dposRow = (lane < 32) ? __shfl(dposA, row2, 64) : -1;
    if (lane < 32 && dposRow >= 0) {
        uint4 v = *(uint4*)&L[row2 * 12 + ch * 4];
        ((uint4*)(msg + (size_t)dposRow * 16))[ch] = v;
    }
}

// ---- segment sum layer2 (quarter-wave per node)
__global__ __launch_bounds__(256) void k_seg2(
    const unsigned short* __restrict__ msg, const int* __restrict__ nodeoff,
    unsigned short* __restrict__ agg2, int nNodes) {
    int c = threadIdx.x & 15;
    int gq = (int)((blockIdx.x * blockDim.x + threadIdx.x) >> 4);
    int nQ = (int)((gridDim.x * blockDim.x) >> 4);
    for (int n = gq; n < nNodes; n += nQ) {
        int s0 = nodeoff[n], s1 = nodeoff[n + 1];
        float acc = bf2f(agg2[(size_t)n * 16 + c]);
        for (int rr = s0; rr < s1; ++rr) acc += bf2f(msg[(size_t)rr * 16 + c]);
        agg2[(size_t)n * 16 + c] = f2bf(acc);
    }
}

// ---- fallback (atomic) edge kernels, used when ws is too small
__global__ __launch_bounds__(256) void k_edgemm1_at(
    const unsigned short* __restrict__ xbf, const int* __restrict__ src,
    const int* __restrict__ dst, const int* __restrict__ order,
    const int* __restrict__ offs, const unsigned short* __restrict__ W1f,
    unsigned short* __restrict__ agg) {
    int lane = threadIdx.x & 63;
    int wid = (int)(threadIdx.x >> 6);
    int tile = blockIdx.x * 4 + wid;
    int t16 = tile * 16;
    if (t16 >= offs[8]) return;
    int r = 0;
#pragma unroll
    for (int q = 1; q < 8; ++q) r += (t16 >= offs[q]);
    const unsigned short* Wf = W1f + r * 4096;
    bf16x8 b[2][4];
#pragma unroll
    for (int kt = 0; kt < 2; ++kt)
#pragma unroll
        for (int nt = 0; nt < 4; ++nt)
            b[kt][nt] = *(const bf16x8*)(Wf + (kt * 4 + nt) * 512 + lane * 8);
    int idxA = order[t16 + (lane & 15)];
    int sA = idxA >= 0 ? src[idxA] : 0;
    const unsigned short* xrow = xbf + (size_t)sA * 64 + ((lane >> 4) << 3);
    bf16x8 a[2];
    a[0] = *(const bf16x8*)(xrow);
    a[1] = *(const bf16x8*)(xrow + 32);
    f32x4 z = {0.f, 0.f, 0.f, 0.f};
    f32x4 acc[4] = {z, z, z, z};
#pragma unroll
    for (int kt = 0; kt < 2; ++kt)
#pragma unroll
        for (int nt = 0; nt < 4; ++nt)
            acc[nt] = __builtin_amdgcn_mfma_f32_16x16x32_bf16(a[kt], b[kt][nt], acc[nt], 0, 0, 0);
    const int even = !(lane & 1);
#pragma unroll
    for (int reg = 0; reg < 4; ++reg) {
        int row = ((lane >> 4) << 2) + reg;
        int idxD = order[t16 + row];
        if (idxD < 0) continue;
        int d = dst[idxD];
        unsigned short* ap = agg + (size_t)d * 64 + (lane & 14);
#pragma unroll
        for (int nt = 0; nt < 4; ++nt) {
            float mine = acc[nt][reg];
            float oth = __shfl_xor(mine, 1, 64);
            unsigned pk = even ? ((unsigned)f2bf(mine) | ((unsigned)f2bf(oth) << 16))
                               : ((unsigned)f2bf(oth) | ((unsigned)f2bf(mine) << 16));
            if (even ? (nt < 2) : (nt >= 2)) pkAddBf16(ap + nt * 16, pk);
        }
    }
}

__global__ __launch_bounds__(256) void k_edgemm2_at(
    const unsigned short* __restrict__ h, const int* __restrict__ src,
    const int* __restrict__ dst, const int* __restrict__ order,
    const int* __restrict__ offs, const unsigned short* __restrict__ W2f,
    unsigned short* __restrict__ agg2) {
    int lane = threadIdx.x & 63;
    int wid = (int)(threadIdx.x >> 6);
    int tile = blockIdx.x * 4 + wid;
    int t16 = tile * 16;
    if (t16 >= offs[8]) return;
    int r = 0;
#pragma unroll
    for (int q = 1; q < 8; ++q) r += (t16 >= offs[q]);
    const unsigned short* Wf = W2f + r * 1024;
    bf16x8 b[2];
    b[0] = *(const bf16x8*)(Wf + lane * 8);
    b[1] = *(const bf16x8*)(Wf + 512 + lane * 8);
    int idxA = order[t16 + (lane & 15)];
    int sA = idxA >= 0 ? src[idxA] : 0;
    const unsigned short* hrow = h + (size_t)sA * 64 + ((lane >> 4) << 3);
    bf16x8 a[2];
    a[0] = *(const bf16x8*)(hrow);
    a[1] = *(const bf16x8*)(hrow + 32);
    f32x4 acc = {0.f, 0.f, 0.f, 0.f};
    acc = __builtin_amdgcn_mfma_f32_16x16x32_bf16(a[0], b[0], acc, 0, 0, 0);
    acc = __builtin_amdgcn_mfma_f32_16x16x32_bf16(a[1], b[1], acc, 0, 0, 0);
    const int even = !(lane & 1);
#pragma unroll
    for (int reg = 0; reg < 4; ++reg) {
        int row = ((lane >> 4) << 2) + reg;
        int idxD = order[t16 + row];
        if (idxD < 0) continue;
        float mine = acc[reg];
        float oth = __shfl_xor(mine, 1, 64);
        int d = dst[idxD];
        unsigned pk = even ? ((unsigned)f2bf(mine) | ((unsigned)f2bf(oth) << 16))
                           : ((unsigned)f2bf(oth) | ((unsigned)f2bf(mine) << 16));
        if (even ? (reg < 2) : (reg >= 2))
            pkAddBf16(agg2 + (size_t)d * 16 + (lane & 14), pk);
    }
}

__global__ void k_bounds(const int* __restrict__ gid, int* __restrict__ start, int nNodes) {
    int t = blockIdx.x * blockDim.x + threadIdx.x;
    if (t > 64) return;
    int lo = 0, hi = nNodes;
    while (lo < hi) {
        int mid = (lo + hi) >> 1;
        if (gid[mid] < t) lo = mid + 1; else hi = mid;
    }
    start[t] = lo;
}

__global__ __launch_bounds__(256) void k_pool(
    const unsigned short* __restrict__ agg2, const int* __restrict__ start,
    float* __restrict__ out) {
    __shared__ float sm[256];
    int g = blockIdx.x;
    int t = threadIdx.x;
    int c = t & 15, idx = t >> 4;
    int s0 = start[g], s1 = start[g + 1];
    float acc = 0.f;
    for (int n = s0 + idx; n < s1; n += 16) acc += fmaxf(bf2f(agg2[(size_t)n * 16 + c]), 0.f);
    sm[t] = acc;
    __syncthreads();
#pragma unroll
    for (int off = 128; off >= 16; off >>= 1) {
        if (t < off) sm[t] += sm[t + off];
        __syncthreads();
    }
    if (t < 16) {
        float cnt = (float)(s1 - s0);
        out[g * 16 + t] = sm[t] / fmaxf(cnt, 1.f);
    }
}

extern "C" void kernel_launch(void* const* d_in, const int* in_sizes, int n_in,
                              void* d_out, int out_size, void* d_ws, size_t ws_size,
                              hipStream_t stream) {
    const float* x      = (const float*)d_in[0];
    const int*   src    = (const int*)d_in[1];
    const int*   dst    = (const int*)d_in[2];
    const int*   et     = (const int*)d_in[3];
    const int*   gid    = (const int*)d_in[4];
    const float* bases1 = (const float*)d_in[5];
    const float* coeff1 = (const float*)d_in[6];
    const float* wself1 = (const float*)d_in[7];
    const float* bias1  = (const float*)d_in[8];
    const float* bases2 = (const float*)d_in[9];
    const float* coeff2 = (const float*)d_in[10];
    const float* wself2 = (const float*)d_in[11];
    const float* bias2  = (const float*)d_in[12];
    float* out = (float*)d_out;

    int nNodes = in_sizes[0] / 64;
    int nE = in_sizes[1];

    char* ws = (char*)d_ws;
    unsigned short* W1f  = (unsigned short*)(ws);
    unsigned short* W2f  = (unsigned short*)(ws + 65536);
    unsigned short* xbf  = (unsigned short*)(ws + 81920);
    unsigned short* agg1 = (unsigned short*)(ws + 12881920);
    unsigned short* agg2 = (unsigned short*)(ws + 25681920);
    int*   order   = (int*)(ws + 28881920);
    int*   wh      = (int*)(ws + 32882432);
    int*   wbase   = (int*)(ws + 33013504);
    int*   offs    = (int*)(ws + 33144576);
    int*   start   = (int*)(ws + 33144640);
    int*   deg     = (int*)(ws + 33145152);
    int*   nodeoff = (int*)(ws + 33545152);
    int*   cursor  = (int*)(ws + 33945280);
    int*   btot    = (int*)(ws + 34345280);
    int*   boff    = (int*)(ws + 34347328);
    int*   dpos    = (int*)(ws + 34349376);
    unsigned short* msg = (unsigned short*)(ws + 38349568);
    const size_t NEED = 38349568ull + (size_t)nE * 64 * 2;
    bool big = ws_size >= NEED;

    int nWaves = (nE + WCHUNK - 1) / WCHUNK;
    int hb = (nWaves * 64 + 255) / 256;
    int tiles = (nE + 128) / 16;
    int eb = (tiles + 3) / 4;
    int nB = (nNodes + 255) / 256;

    hipLaunchKernelGGL(k_weights, dim3(8), dim3(256), 0, stream,
                       bases1, coeff1, bases2, coeff2, W1f, W2f);
    hipLaunchKernelGGL(k_xcast, dim3(2048), dim3(256), 0, stream,
                       x, xbf, nNodes * 8);
    hipLaunchKernelGGL(k_whist, dim3(hb), dim3(256), 0, stream, et, wh, nE, nWaves);
    hipLaunchKernelGGL(k_scan2, dim3(1), dim3(512), 0, stream,
                       wh, wbase, offs, order, nWaves);
    hipLaunchKernelGGL(k_scatter2, dim3(hb), dim3(256), 0, stream,
                       et, wbase, order, nE, nWaves);
    hipLaunchKernelGGL(k_lin1, dim3(512), dim3(256), 0, stream,
                       x, wself1, bias1, agg1, nNodes);
    if (big) {
        hipLaunchKernelGGL(k_zero, dim3(nB), dim3(256), 0, stream, deg, nNodes);
        hipLaunchKernelGGL(k_histdst, dim3(1024), dim3(256), 0, stream, dst, deg, nE);
        hipLaunchKernelGGL(k_scanblk, dim3(nB), dim3(256), 0, stream,
                           deg, nodeoff, btot, nNodes);
        hipLaunchKernelGGL(k_scantop, dim3(1), dim3(512), 0, stream, btot, boff, nB);
        hipLaunchKernelGGL(k_scanadd, dim3(nB + 1), dim3(256), 0, stream,
                           nodeoff, boff, cursor, nNodes, nE);
        hipLaunchKernelGGL(k_rank, dim3(1024), dim3(256), 0, stream,
                           dst, cursor, dpos, nE);
        hipLaunchKernelGGL(k_edgemm1, dim3(eb), dim3(256), 0, stream,
                           xbf, src, order, offs, W1f, dpos, msg);
        hipLaunchKernelGGL(k_seg1, dim3(1024), dim3(256), 0, stream,
                           msg, nodeoff, agg1, nNodes);
        hipLaunchKernelGGL(k_lin2, dim3(512), dim3(256), 0, stream,
                           agg1, wself2, bias2, agg2, nNodes);
        hipLaunchKernelGGL(k_edgemm2, dim3(eb), dim3(256), 0, stream,
                           agg1, src, order, offs, W2f, dpos, msg);
        hipLaunchKernelGGL(k_seg2, dim3(512), dim3(256), 0, stream,
                           msg, nodeoff, agg2, nNodes);
    } else {
        hipLaunchKernelGGL(k_edgemm1_at, dim3(eb), dim3(256), 0, stream,
                           xbf, src, dst, order, offs, W1f, agg1);
        hipLaunchKernelGGL(k_lin2, dim3(512), dim3(256), 0, stream,
                           agg1, wself2, bias2, agg2, nNodes);
        hipLaunchKernelGGL(k_edgemm2_at, dim3(eb), dim3(256), 0, stream,
                           agg1, src, dst, order, offs, W2f, agg2);
    }
    hipLaunchKernelGGL(k_bounds, dim3(1), dim3(128), 0, stream, gid, start, nNodes);
    hipLaunchKernelGGL(k_pool, dim3(64), dim3(256), 0, stream, agg2, start, out);
}

// Round 7
// 384.784 us; speedup vs baseline: 1.4783x; 1.2557x over previous
//
#include <hip/hip_runtime.h>

// ---------------------------------------------------------------------------
// RGCN (basis decomposition, 2 layers) + mean-pool.
// Edge phase: relation-bucketed 16-edge tiles -> bf16 MFMA (16x16x32) ->
// LDS transpose -> plain full-line stores into dst-sorted msg buffer ->
// segmented sum (no atomics in the hot path). Counting sorts by relation
// (for tile uniformity) and by dst (for the segment sum).
// Round 6: k_scan2 parallelized (one wave per relation, shfl_up scan).
// Round 7: k_seg1/k_seg2 vectorized (uint2 8B/lane, quarter-/4-lane groups)
// — were latency-bound at 2B/lane scalar bf16 loads.
//
// ws layout (bytes): unchanged from round 6 (see comment history).
// total need = 166,349,568 B; fallback to atomic path if ws smaller.
// ---------------------------------------------------------------------------

typedef __attribute__((ext_vector_type(8))) short bf16x8;
typedef __attribute__((ext_vector_type(4))) float f32x4;

#define WCHUNK 2048

__device__ __forceinline__ unsigned short f2bf(float f) {
    unsigned u = __float_as_uint(f);
    unsigned r = u + 0x7FFFu + ((u >> 16) & 1u);   // RNE
    return (unsigned short)(r >> 16);
}

__device__ __forceinline__ float bf2f(unsigned short u) {
    return __uint_as_float(((unsigned)u) << 16);
}

__device__ __forceinline__ float bcast(float v, int l) {
    return __uint_as_float(__builtin_amdgcn_readlane(__float_as_uint(v), l));
}

__device__ __forceinline__ void pkAddBf16(unsigned short* addr, unsigned pk) {
    asm volatile("global_atomic_pk_add_bf16 %0, %1, off"
                 :: "v"((unsigned long long)(size_t)addr), "v"(pk));
}

// ---- weights in B-fragment order (16x16x32 bf16): lane l holds
// B[k = kt*32+(l>>4)*8+j][n = nt*16+(l&15)], j=0..7
__global__ __launch_bounds__(256) void k_weights(
    const float* __restrict__ bases1, const float* __restrict__ coeff1,
    const float* __restrict__ bases2, const float* __restrict__ coeff2,
    unsigned short* __restrict__ W1f, unsigned short* __restrict__ W2f) {
    int r = blockIdx.x;
    int tid = threadIdx.x;
    float c1[8], c2[8];
#pragma unroll
    for (int b = 0; b < 8; ++b) { c1[b] = coeff1[r * 8 + b]; c2[b] = coeff2[r * 8 + b]; }
    for (int idx = tid; idx < 4096; idx += 256) {
        int j = idx & 7, lane = (idx >> 3) & 63, nt = (idx >> 9) & 3, kt = idx >> 11;
        int i = kt * 32 + ((lane >> 4) << 3) + j;
        int jo = nt * 16 + (lane & 15);
        float s = 0.f;
#pragma unroll
        for (int b = 0; b < 8; ++b) s = fmaf(c1[b], bases1[b * 4096 + i * 64 + jo], s);
        W1f[r * 4096 + idx] = f2bf(s);
    }
    for (int idx = tid; idx < 1024; idx += 256) {
        int j = idx & 7, lane = (idx >> 3) & 63, kt = idx >> 9;
        int i = kt * 32 + ((lane >> 4) << 3) + j;
        int jo = lane & 15;
        float s = 0.f;
#pragma unroll
        for (int b = 0; b < 8; ++b) s = fmaf(c2[b], bases2[b * 1024 + i * 16 + jo], s);
        W2f[r * 1024 + idx] = f2bf(s);
    }
}

__global__ __launch_bounds__(256) void k_xcast(
    const float* __restrict__ x, unsigned short* __restrict__ xbf, int n8) {
    int stride = gridDim.x * blockDim.x;
    for (int i = blockIdx.x * blockDim.x + threadIdx.x; i < n8; i += stride) {
        f32x4 u0 = *(const f32x4*)(x + (size_t)i * 8);
        f32x4 u1 = *(const f32x4*)(x + (size_t)i * 8 + 4);
        bf16x8 t;
        t[0] = (short)f2bf(u0[0]); t[1] = (short)f2bf(u0[1]);
        t[2] = (short)f2bf(u0[2]); t[3] = (short)f2bf(u0[3]);
        t[4] = (short)f2bf(u1[0]); t[5] = (short)f2bf(u1[1]);
        t[6] = (short)f2bf(u1[2]); t[7] = (short)f2bf(u1[3]);
        *(bf16x8*)(xbf + (size_t)i * 8) = t;
    }
}

// ---- relation counting sort (per-wave hist -> scan -> rank scatter)
__global__ __launch_bounds__(256) void k_whist(
    const int* __restrict__ et, int* __restrict__ wh, int nE, int nWaves) {
    int wid = (int)((blockIdx.x * blockDim.x + threadIdx.x) >> 6);
    int lane = threadIdx.x & 63;
    if (wid >= nWaves) return;
    int e0 = wid * WCHUNK, e1 = min(e0 + WCHUNK, nE);
    int c0 = 0, c1 = 0, c2 = 0, c3 = 0, c4 = 0, c5 = 0, c6 = 0, c7 = 0;
    for (int c = e0; c < e1; c += 64) {
        int e = c + lane;
        int r = (e < e1) ? et[e] : -1;
        c0 += __popcll(__ballot(r == 0)); c1 += __popcll(__ballot(r == 1));
        c2 += __popcll(__ballot(r == 2)); c3 += __popcll(__ballot(r == 3));
        c4 += __popcll(__ballot(r == 4)); c5 += __popcll(__ballot(r == 5));
        c6 += __popcll(__ballot(r == 6)); c7 += __popcll(__ballot(r == 7));
    }
    int v = c0;
    if (lane == 1) v = c1; if (lane == 2) v = c2; if (lane == 3) v = c3;
    if (lane == 4) v = c4; if (lane == 5) v = c5; if (lane == 6) v = c6;
    if (lane == 7) v = c7;
    if (lane < 8) wh[wid * 8 + lane] = v;
}

// ---- parallel scan: one wave per relation; chunked shfl_up scan with carry
__global__ __launch_bounds__(512) void k_scan2(
    const int* __restrict__ wh, int* __restrict__ wbase,
    int* __restrict__ offs, int* __restrict__ order, int nWaves) {
    __shared__ int tot[8];
    __shared__ int off[9];
    int rel = (int)(threadIdx.x >> 6);   // 0..7
    int lane = (int)(threadIdx.x & 63);
    int carry = 0;
    for (int c = 0; c < nWaves; c += 64) {
        int w = c + lane;
        int v = (w < nWaves) ? wh[w * 8 + rel] : 0;
        int s = v;
#pragma unroll
        for (int d = 1; d < 64; d <<= 1) {
            int t = __shfl_up(s, d, 64);
            if (lane >= d) s += t;
        }
        if (w < nWaves) wbase[w * 8 + rel] = carry + s - v;   // exclusive
        carry += __shfl(s, 63, 64);
    }
    if (lane == 0) tot[rel] = carry;
    __syncthreads();
    if (threadIdx.x == 0) {
        int o = 0;
        for (int q = 0; q < 8; ++q) { off[q] = o; offs[q] = o; o += (tot[q] + 15) & ~15; }
        off[8] = o; offs[8] = o;
    }
    __syncthreads();
    int base = off[rel];
    for (int w = lane; w < nWaves; w += 64) wbase[w * 8 + rel] += base;
    for (int p = base + tot[rel] + lane; p < off[rel + 1]; p += 64) order[p] = -1;
}

__global__ __launch_bounds__(256) void k_scatter2(
    const int* __restrict__ et, const int* __restrict__ wbase,
    int* __restrict__ order, int nE, int nWaves) {
    int wid = (int)((blockIdx.x * blockDim.x + threadIdx.x) >> 6);
    int lane = threadIdx.x & 63;
    if (wid >= nWaves) return;
    int e0 = wid * WCHUNK, e1 = min(e0 + WCHUNK, nE);
    int cu0 = wbase[wid * 8 + 0], cu1 = wbase[wid * 8 + 1];
    int cu2 = wbase[wid * 8 + 2], cu3 = wbase[wid * 8 + 3];
    int cu4 = wbase[wid * 8 + 4], cu5 = wbase[wid * 8 + 5];
    int cu6 = wbase[wid * 8 + 6], cu7 = wbase[wid * 8 + 7];
    unsigned long long below = (1ull << lane) - 1ull;
    for (int c = e0; c < e1; c += 64) {
        int e = c + lane;
        int r = (e < e1) ? et[e] : -1;
        int pos = -1;
#define DOREL(RR, CU) { unsigned long long m = __ballot(r == RR); \
        if (r == RR) pos = CU + __popcll(m & below); CU += __popcll(m); }
        DOREL(0, cu0) DOREL(1, cu1) DOREL(2, cu2) DOREL(3, cu3)
        DOREL(4, cu4) DOREL(5, cu5) DOREL(6, cu6) DOREL(7, cu7)
#undef DOREL
        if (pos >= 0) order[pos] = e;
    }
}

// ---- dst counting sort: deg histogram -> block scan -> rank
__global__ __launch_bounds__(256) void k_zero(int* __restrict__ p, int n) {
    int i = blockIdx.x * blockDim.x + threadIdx.x;
    if (i < n) p[i] = 0;
}

__global__ __launch_bounds__(256) void k_histdst(
    const int* __restrict__ dst, int* __restrict__ deg, int nE) {
    int stride = gridDim.x * blockDim.x;
    for (int e = blockIdx.x * blockDim.x + threadIdx.x; e < nE; e += stride)
        atomicAdd(&deg[dst[e]], 1);
}

__global__ __launch_bounds__(256) void k_scanblk(
    const int* __restrict__ deg, int* __restrict__ nodeoff,
    int* __restrict__ btot, int nNodes) {
    __shared__ int sm[256];
    int tid = threadIdx.x;
    int n = blockIdx.x * 256 + tid;
    int d = (n < nNodes) ? deg[n] : 0;
    sm[tid] = d;
    __syncthreads();
#pragma unroll
    for (int off = 1; off < 256; off <<= 1) {
        int v = (tid >= off) ? sm[tid - off] : 0;
        __syncthreads();
        sm[tid] += v;
        __syncthreads();
    }
    if (n < nNodes) nodeoff[n] = sm[tid] - d;       // exclusive within block
    if (tid == 255) btot[blockIdx.x] = sm[255];
}

__global__ void k_scantop(const int* __restrict__ btot, int* __restrict__ boff, int nB) {
    __shared__ int sm[512];
    int t = threadIdx.x;
    int d = (t < nB) ? btot[t] : 0;
    sm[t] = d;
    __syncthreads();
#pragma unroll
    for (int off = 1; off < 512; off <<= 1) {
        int v = (t >= off) ? sm[t - off] : 0;
        __syncthreads();
        sm[t] += v;
        __syncthreads();
    }
    if (t < nB) boff[t] = sm[t] - d;                // exclusive
}

__global__ __launch_bounds__(256) void k_scanadd(
    int* __restrict__ nodeoff, const int* __restrict__ boff,
    int* __restrict__ cursor, int nNodes, int nE) {
    int n = blockIdx.x * 256 + threadIdx.x;
    if (n < nNodes) {
        int v = nodeoff[n] + boff[n >> 8];
        nodeoff[n] = v;
        cursor[n] = v;
    } else if (n == nNodes) {
        nodeoff[n] = nE;
    }
}

__global__ __launch_bounds__(256) void k_rank(
    const int* __restrict__ dst, int* __restrict__ cursor,
    int* __restrict__ dpos, int nE) {
    int stride = gridDim.x * blockDim.x;
    for (int e = blockIdx.x * blockDim.x + threadIdx.x; e < nE; e += stride)
        dpos[e] = atomicAdd(&cursor[dst[e]], 1);
}

// ---- self-loop layer1: agg1 = bf16(x @ wself1 + bias1)
__global__ __launch_bounds__(256) void k_lin1(
    const float* __restrict__ x, const float* __restrict__ wself,
    const float* __restrict__ bias, unsigned short* __restrict__ agg, int nNodes) {
    int lane = threadIdx.x & 63;
    int gw = (int)((blockIdx.x * blockDim.x + threadIdx.x) >> 6);
    int nW = (int)((gridDim.x * blockDim.x) >> 6);
    float w[64];
#pragma unroll
    for (int i = 0; i < 64; ++i) w[i] = wself[i * 64 + lane];
    float bj = bias[lane];
    for (int n = gw; n < nNodes; n += nW) {
        float xv = x[n * 64 + lane];
        float a0 = 0.f, a1 = 0.f, a2 = 0.f, a3 = 0.f;
#pragma unroll
        for (int i = 0; i < 64; i += 4) {
            a0 = fmaf(bcast(xv, i + 0), w[i + 0], a0);
            a1 = fmaf(bcast(xv, i + 1), w[i + 1], a1);
            a2 = fmaf(bcast(xv, i + 2), w[i + 2], a2);
            a3 = fmaf(bcast(xv, i + 3), w[i + 3], a3);
        }
        agg[(size_t)n * 64 + lane] = f2bf(bj + ((a0 + a1) + (a2 + a3)));
    }
}

// ---- edge GEMM layer1 -> msg rows (dst-sorted, plain full-line stores)
__global__ __launch_bounds__(256) void k_edgemm1(
    const unsigned short* __restrict__ xbf, const int* __restrict__ src,
    const int* __restrict__ order, const int* __restrict__ offs,
    const unsigned short* __restrict__ W1f, const int* __restrict__ dpos,
    unsigned short* __restrict__ msg) {
    __shared__ unsigned lds[4][16 * 36];
    int lane = threadIdx.x & 63;
    int wid = (int)(threadIdx.x >> 6);
    int tile = blockIdx.x * 4 + wid;
    int t16 = tile * 16;
    if (t16 >= offs[8]) return;
    int r = 0;
#pragma unroll
    for (int q = 1; q < 8; ++q) r += (t16 >= offs[q]);
    const unsigned short* Wf = W1f + r * 4096;
    bf16x8 b[2][4];
#pragma unroll
    for (int kt = 0; kt < 2; ++kt)
#pragma unroll
        for (int nt = 0; nt < 4; ++nt)
            b[kt][nt] = *(const bf16x8*)(Wf + (kt * 4 + nt) * 512 + lane * 8);
    int idxA = order[t16 + (lane & 15)];
    int sA = idxA >= 0 ? src[idxA] : 0;
    int dposA = idxA >= 0 ? dpos[idxA] : -1;
    const unsigned short* xrow = xbf + (size_t)sA * 64 + ((lane >> 4) << 3);
    bf16x8 a[2];
    a[0] = *(const bf16x8*)(xrow);
    a[1] = *(const bf16x8*)(xrow + 32);
    f32x4 z = {0.f, 0.f, 0.f, 0.f};
    f32x4 acc[4] = {z, z, z, z};
#pragma unroll
    for (int kt = 0; kt < 2; ++kt)
#pragma unroll
        for (int nt = 0; nt < 4; ++nt)
            acc[nt] = __builtin_amdgcn_mfma_f32_16x16x32_bf16(a[kt], b[kt][nt], acc[nt], 0, 0, 0);
    unsigned* L = lds[wid];
    const int even = !(lane & 1);
    const int cpair = (lane & 14) >> 1;
#pragma unroll
    for (int reg = 0; reg < 4; ++reg) {
        int row = ((lane >> 4) << 2) + reg;
#pragma unroll
        for (int nt = 0; nt < 4; ++nt) {
            float mine = acc[nt][reg];
            float oth = __shfl_xor(mine, 1, 64);
            unsigned pk = even ? ((unsigned)f2bf(mine) | ((unsigned)f2bf(oth) << 16))
                               : ((unsigned)f2bf(oth) | ((unsigned)f2bf(mine) << 16));
            if (even ? (nt < 2) : (nt >= 2)) L[row * 36 + cpair + nt * 8] = pk;
        }
    }
    // same-wave LDS RAW; compiler inserts lgkmcnt
    int row2 = lane >> 2, ch = lane & 3;
    int dposRow = __shfl(dposA, row2, 64);
    if (dposRow >= 0) {
        uint4 v0 = *(uint4*)&L[row2 * 36 + ch * 4];
        uint4 v1 = *(uint4*)&L[row2 * 36 + 16 + ch * 4];
        uint4* mp = (uint4*)(msg + (size_t)dposRow * 64);
        mp[ch] = v0;
        mp[4 + ch] = v1;
    }
}

// ---- segment sum layer1 (16-lane group per node, uint2 8B/lane loads)
__global__ __launch_bounds__(256) void k_seg1(
    const unsigned short* __restrict__ msg, const int* __restrict__ nodeoff,
    unsigned short* __restrict__ agg1, int nNodes) {
    int gl = threadIdx.x & 15;                 // 4 cols per lane
    int grp = (int)((blockIdx.x * blockDim.x + threadIdx.x) >> 4);
    int nG = (int)((gridDim.x * blockDim.x) >> 4);
    for (int n = grp; n < nNodes; n += nG) {
        int s0 = nodeoff[n], s1 = nodeoff[n + 1];
        uint2 v = *(const uint2*)(agg1 + (size_t)n * 64 + gl * 4);
        float a0 = bf2f((unsigned short)v.x), a1 = bf2f((unsigned short)(v.x >> 16));
        float a2 = bf2f((unsigned short)v.y), a3 = bf2f((unsigned short)(v.y >> 16));
        for (int rr = s0; rr < s1; ++rr) {
            uint2 m = *(const uint2*)(msg + (size_t)rr * 64 + gl * 4);
            a0 += bf2f((unsigned short)m.x); a1 += bf2f((unsigned short)(m.x >> 16));
            a2 += bf2f((unsigned short)m.y); a3 += bf2f((unsigned short)(m.y >> 16));
        }
        uint2 p;
        p.x = (unsigned)f2bf(a0) | ((unsigned)f2bf(a1) << 16);
        p.y = (unsigned)f2bf(a2) | ((unsigned)f2bf(a3) << 16);
        *(uint2*)(agg1 + (size_t)n * 64 + gl * 4) = p;
    }
}

// ---- relu (in-place) + self-loop layer2 -> agg2 init
__global__ __launch_bounds__(256) void k_lin2(
    unsigned short* __restrict__ agg1, const float* __restrict__ wself,
    const float* __restrict__ bias, unsigned short* __restrict__ agg2, int nNodes) {
    int lane = threadIdx.x & 63;
    int j = lane & 15;
    int gw = (int)((blockIdx.x * blockDim.x + threadIdx.x) >> 6);
    int nW = (int)((gridDim.x * blockDim.x) >> 6);
    float w[64];
#pragma unroll
    for (int i = 0; i < 64; ++i) w[i] = wself[i * 16 + j];
    float bj = bias[j];
    for (int n = gw; n < nNodes; n += nW) {
        unsigned short raw = agg1[(size_t)n * 64 + lane];
        unsigned short rbf = (raw & 0x8000u) ? (unsigned short)0 : raw;
        agg1[(size_t)n * 64 + lane] = rbf;          // h in place
        float hv = bf2f(rbf);
        float a0 = 0.f, a1 = 0.f, a2 = 0.f, a3 = 0.f;
#pragma unroll
        for (int i = 0; i < 64; i += 4) {
            a0 = fmaf(bcast(hv, i + 0), w[i + 0], a0);
            a1 = fmaf(bcast(hv, i + 1), w[i + 1], a1);
            a2 = fmaf(bcast(hv, i + 2), w[i + 2], a2);
            a3 = fmaf(bcast(hv, i + 3), w[i + 3], a3);
        }
        if (lane < 16) agg2[(size_t)n * 16 + lane] = f2bf(bj + ((a0 + a1) + (a2 + a3)));
    }
}

// ---- edge GEMM layer2 -> msg rows (16 cols)
__global__ __launch_bounds__(256) void k_edgemm2(
    const unsigned short* __restrict__ h, const int* __restrict__ src,
    const int* __restrict__ order, const int* __restrict__ offs,
    const unsigned short* __restrict__ W2f, const int* __restrict__ dpos,
    unsigned short* __restrict__ msg) {
    __shared__ unsigned lds[4][16 * 12];
    int lane = threadIdx.x & 63;
    int wid = (int)(threadIdx.x >> 6);
    int tile = blockIdx.x * 4 + wid;
    int t16 = tile * 16;
    if (t16 >= offs[8]) return;
    int r = 0;
#pragma unroll
    for (int q = 1; q < 8; ++q) r += (t16 >= offs[q]);
    const unsigned short* Wf = W2f + r * 1024;
    bf16x8 b[2];
    b[0] = *(const bf16x8*)(Wf + lane * 8);
    b[1] = *(const bf16x8*)(Wf + 512 + lane * 8);
    int idxA = order[t16 + (lane & 15)];
    int sA = idxA >= 0 ? src[idxA] : 0;
    int dposA = idxA >= 0 ? dpos[idxA] : -1;
    const unsigned short* hrow = h + (size_t)sA * 64 + ((lane >> 4) << 3);
    bf16x8 a[2];
    a[0] = *(const bf16x8*)(hrow);
    a[1] = *(const bf16x8*)(hrow + 32);
    f32x4 acc = {0.f, 0.f, 0.f, 0.f};
    acc = __builtin_amdgcn_mfma_f32_16x16x32_bf16(a[0], b[0], acc, 0, 0, 0);
    acc = __builtin_amdgcn_mfma_f32_16x16x32_bf16(a[1], b[1], acc, 0, 0, 0);
    unsigned* L = lds[wid];
    const int even = !(lane & 1);
    const int cpair = (lane & 14) >> 1;
#pragma unroll
    for (int reg = 0; reg < 4; ++reg) {
        int row = ((lane >> 4) << 2) + reg;
        float mine = acc[reg];
        float oth = __shfl_xor(mine, 1, 64);
        unsigned pk = even ? ((unsigned)f2bf(mine) | ((unsigned)f2bf(oth) << 16))
                           : ((unsigned)f2bf(oth) | ((unsigned)f2bf(mine) << 16));
        if (even ? (reg < 2) : (reg >= 2)) L[row * 12 + cpair] = pk;
    }
    int row2 = lane >> 1, ch = lane & 1;
    int dposRow = (lane < 32) ? __shfl(dposA, row2, 64) : -1;
    if (lane < 32 && dposRow >= 0) {
        uint4 v = *(uint4*)&L[row2 * 12 + ch * 4];
        ((uint4*)(msg + (size_t)dposRow * 16))[ch] = v;
    }
}

// ---- segment sum layer2 (4-lane group per node, uint2 8B/lane loads)
__global__ __launch_bounds__(256) void k_seg2(
    const unsigned short* __restrict__ msg, const int* __restrict__ nodeoff,
    unsigned short* __restrict__ agg2, int nNodes) {
    int gl = threadIdx.x & 3;                  // 4 cols per lane
    int grp = (int)((blockIdx.x * blockDim.x + threadIdx.x) >> 2);
    int nG = (int)((gridDim.x * blockDim.x) >> 2);
    for (int n = grp; n < nNodes; n += nG) {
        int s0 = nodeoff[n], s1 = nodeoff[n + 1];
        uint2 v = *(const uint2*)(agg2 + (size_t)n * 16 + gl * 4);
        float a0 = bf2f((unsigned short)v.x), a1 = bf2f((unsigned short)(v.x >> 16));
        float a2 = bf2f((unsigned short)v.y), a3 = bf2f((unsigned short)(v.y >> 16));
        for (int rr = s0; rr < s1; ++rr) {
            uint2 m = *(const uint2*)(msg + (size_t)rr * 16 + gl * 4);
            a0 += bf2f((unsigned short)m.x); a1 += bf2f((unsigned short)(m.x >> 16));
            a2 += bf2f((unsigned short)m.y); a3 += bf2f((unsigned short)(m.y >> 16));
        }
        uint2 p;
        p.x = (unsigned)f2bf(a0) | ((unsigned)f2bf(a1) << 16);
        p.y = (unsigned)f2bf(a2) | ((unsigned)f2bf(a3) << 16);
        *(uint2*)(agg2 + (size_t)n * 16 + gl * 4) = p;
    }
}

// ---- fallback (atomic) edge kernels, used when ws is too small
__global__ __launch_bounds__(256) void k_edgemm1_at(
    const unsigned short* __restrict__ xbf, const int* __restrict__ src,
    const int* __restrict__ dst, const int* __restrict__ order,
    const int* __restrict__ offs, const unsigned short* __restrict__ W1f,
    unsigned short* __restrict__ agg) {
    int lane = threadIdx.x & 63;
    int wid = (int)(threadIdx.x >> 6);
    int tile = blockIdx.x * 4 + wid;
    int t16 = tile * 16;
    if (t16 >= offs[8]) return;
    int r = 0;
#pragma unroll
    for (int q = 1; q < 8; ++q) r += (t16 >= offs[q]);
    const unsigned short* Wf = W1f + r * 4096;
    bf16x8 b[2][4];
#pragma unroll
    for (int kt = 0; kt < 2; ++kt)
#pragma unroll
        for (int nt = 0; nt < 4; ++nt)
            b[kt][nt] = *(const bf16x8*)(Wf + (kt * 4 + nt) * 512 + lane * 8);
    int idxA = order[t16 + (lane & 15)];
    int sA = idxA >= 0 ? src[idxA] : 0;
    const unsigned short* xrow = xbf + (size_t)sA * 64 + ((lane >> 4) << 3);
    bf16x8 a[2];
    a[0] = *(const bf16x8*)(xrow);
    a[1] = *(const bf16x8*)(xrow + 32);
    f32x4 z = {0.f, 0.f, 0.f, 0.f};
    f32x4 acc[4] = {z, z, z, z};
#pragma unroll
    for (int kt = 0; kt < 2; ++kt)
#pragma unroll
        for (int nt = 0; nt < 4; ++nt)
            acc[nt] = __builtin_amdgcn_mfma_f32_16x16x32_bf16(a[kt], b[kt][nt], acc[nt], 0, 0, 0);
    const int even = !(lane & 1);
#pragma unroll
    for (int reg = 0; reg < 4; ++reg) {
        int row = ((lane >> 4) << 2) + reg;
        int idxD = order[t16 + row];
        if (idxD < 0) continue;
        int d = dst[idxD];
        unsigned short* ap = agg + (size_t)d * 64 + (lane & 14);
#pragma unroll
        for (int nt = 0; nt < 4; ++nt) {
            float mine = acc[nt][reg];
            float oth = __shfl_xor(mine, 1, 64);
            unsigned pk = even ? ((unsigned)f2bf(mine) | ((unsigned)f2bf(oth) << 16))
                               : ((unsigned)f2bf(oth) | ((unsigned)f2bf(mine) << 16));
            if (even ? (nt < 2) : (nt >= 2)) pkAddBf16(ap + nt * 16, pk);
        }
    }
}

__global__ __launch_bounds__(256) void k_edgemm2_at(
    const unsigned short* __restrict__ h, const int* __restrict__ src,
    const int* __restrict__ dst, const int* __restrict__ order,
    const int* __restrict__ offs, const unsigned short* __restrict__ W2f,
    unsigned short* __restrict__ agg2) {
    int lane = threadIdx.x & 63;
    int wid = (int)(threadIdx.x >> 6);
    int tile = blockIdx.x * 4 + wid;
    int t16 = tile * 16;
    if (t16 >= offs[8]) return;
    int r = 0;
#pragma unroll
    for (int q = 1; q < 8; ++q) r += (t16 >= offs[q]);
    const unsigned short* Wf = W2f + r * 1024;
    bf16x8 b[2];
    b[0] = *(const bf16x8*)(Wf + lane * 8);
    b[1] = *(const bf16x8*)(Wf + 512 + lane * 8);
    int idxA = order[t16 + (lane & 15)];
    int sA = idxA >= 0 ? src[idxA] : 0;
    const unsigned short* hrow = h + (size_t)sA * 64 + ((lane >> 4) << 3);
    bf16x8 a[2];
    a[0] = *(const bf16x8*)(hrow);
    a[1] = *(const bf16x8*)(hrow + 32);
    f32x4 acc = {0.f, 0.f, 0.f, 0.f};
    acc = __builtin_amdgcn_mfma_f32_16x16x32_bf16(a[0], b[0], acc, 0, 0, 0);
    acc = __builtin_amdgcn_mfma_f32_16x16x32_bf16(a[1], b[1], acc, 0, 0, 0);
    const int even = !(lane & 1);
#pragma unroll
    for (int reg = 0; reg < 4; ++reg) {
        int row = ((lane >> 4) << 2) + reg;
        int idxD = order[t16 + row];
        if (idxD < 0) continue;
        float mine = acc[reg];
        float oth = __shfl_xor(mine, 1, 64);
        int d = dst[idxD];
        unsigned pk = even ? ((unsigned)f2bf(mine) | ((unsigned)f2bf(oth) << 16))
                           : ((unsigned)f2bf(oth) | ((unsigned)f2bf(mine) << 16));
        if (even ? (reg < 2) : (reg >= 2))
            pkAddBf16(agg2 + (size_t)d * 16 + (lane & 14), pk);
    }
}

__global__ void k_bounds(const int* __restrict__ gid, int* __restrict__ start, int nNodes) {
    int t = blockIdx.x * blockDim.x + threadIdx.x;
    if (t > 64) return;
    int lo = 0, hi = nNodes;
    while (lo < hi) {
        int mid = (lo + hi) >> 1;
        if (gid[mid] < t) lo = mid + 1; else hi = mid;
    }
    start[t] = lo;
}

__global__ __launch_bounds__(256) void k_pool(
    const unsigned short* __restrict__ agg2, const int* __restrict__ start,
    float* __restrict__ out) {
    __shared__ float sm[256];
    int g = blockIdx.x;
    int t = threadIdx.x;
    int c = t & 15, idx = t >> 4;
    int s0 = start[g], s1 = start[g + 1];
    float acc = 0.f;
    for (int n = s0 + idx; n < s1; n += 16) acc += fmaxf(bf2f(agg2[(size_t)n * 16 + c]), 0.f);
    sm[t] = acc;
    __syncthreads();
#pragma unroll
    for (int off = 128; off >= 16; off >>= 1) {
        if (t < off) sm[t] += sm[t + off];
        __syncthreads();
    }
    if (t < 16) {
        float cnt = (float)(s1 - s0);
        out[g * 16 + t] = sm[t] / fmaxf(cnt, 1.f);
    }
}

extern "C" void kernel_launch(void* const* d_in, const int* in_sizes, int n_in,
                              void* d_out, int out_size, void* d_ws, size_t ws_size,
                              hipStream_t stream) {
    const float* x      = (const float*)d_in[0];
    const int*   src    = (const int*)d_in[1];
    const int*   dst    = (const int*)d_in[2];
    const int*   et     = (const int*)d_in[3];
    const int*   gid    = (const int*)d_in[4];
    const float* bases1 = (const float*)d_in[5];
    const float* coeff1 = (const float*)d_in[6];
    const float* wself1 = (const float*)d_in[7];
    const float* bias1  = (const float*)d_in[8];
    const float* bases2 = (const float*)d_in[9];
    const float* coeff2 = (const float*)d_in[10];
    const float* wself2 = (const float*)d_in[11];
    const float* bias2  = (const float*)d_in[12];
    float* out = (float*)d_out;

    int nNodes = in_sizes[0] / 64;
    int nE = in_sizes[1];

    char* ws = (char*)d_ws;
    unsigned short* W1f  = (unsigned short*)(ws);
    unsigned short* W2f  = (unsigned short*)(ws + 65536);
    unsigned short* xbf  = (unsigned short*)(ws + 81920);
    unsigned short* agg1 = (unsigned short*)(ws + 12881920);
    unsigned short* agg2 = (unsigned short*)(ws + 25681920);
    int*   order   = (int*)(ws + 28881920);
    int*   wh      = (int*)(ws + 32882432);
    int*   wbase   = (int*)(ws + 33013504);
    int*   offs    = (int*)(ws + 33144576);
    int*   start   = (int*)(ws + 33144640);
    int*   deg     = (int*)(ws + 33145152);
    int*   nodeoff = (int*)(ws + 33545152);
    int*   cursor  = (int*)(ws + 33945280);
    int*   btot    = (int*)(ws + 34345280);
    int*   boff    = (int*)(ws + 34347328);
    int*   dpos    = (int*)(ws + 34349376);
    unsigned short* msg = (unsigned short*)(ws + 38349568);
    const size_t NEED = 38349568ull + (size_t)nE * 64 * 2;
    bool big = ws_size >= NEED;

    int nWaves = (nE + WCHUNK - 1) / WCHUNK;
    int hb = (nWaves * 64 + 255) / 256;
    int tiles = (nE + 128) / 16;
    int eb = (tiles + 3) / 4;
    int nB = (nNodes + 255) / 256;

    hipLaunchKernelGGL(k_weights, dim3(8), dim3(256), 0, stream,
                       bases1, coeff1, bases2, coeff2, W1f, W2f);
    hipLaunchKernelGGL(k_xcast, dim3(2048), dim3(256), 0, stream,
                       x, xbf, nNodes * 8);
    hipLaunchKernelGGL(k_whist, dim3(hb), dim3(256), 0, stream, et, wh, nE, nWaves);
    hipLaunchKernelGGL(k_scan2, dim3(1), dim3(512), 0, stream,
                       wh, wbase, offs, order, nWaves);
    hipLaunchKernelGGL(k_scatter2, dim3(hb), dim3(256), 0, stream,
                       et, wbase, order, nE, nWaves);
    hipLaunchKernelGGL(k_lin1, dim3(512), dim3(256), 0, stream,
                       x, wself1, bias1, agg1, nNodes);
    if (big) {
        hipLaunchKernelGGL(k_zero, dim3(nB), dim3(256), 0, stream, deg, nNodes);
        hipLaunchKernelGGL(k_histdst, dim3(1024), dim3(256), 0, stream, dst, deg, nE);
        hipLaunchKernelGGL(k_scanblk, dim3(nB), dim3(256), 0, stream,
                           deg, nodeoff, btot, nNodes);
        hipLaunchKernelGGL(k_scantop, dim3(1), dim3(512), 0, stream, btot, boff, nB);
        hipLaunchKernelGGL(k_scanadd, dim3(nB + 1), dim3(256), 0, stream,
                           nodeoff, boff, cursor, nNodes, nE);
        hipLaunchKernelGGL(k_rank, dim3(1024), dim3(256), 0, stream,
                           dst, cursor, dpos, nE);
        hipLaunchKernelGGL(k_edgemm1, dim3(eb), dim3(256), 0, stream,
                           xbf, src, order, offs, W1f, dpos, msg);
        hipLaunchKernelGGL(k_seg1, dim3(2048), dim3(256), 0, stream,
                           msg, nodeoff, agg1, nNodes);
        hipLaunchKernelGGL(k_lin2, dim3(512), dim3(256), 0, stream,
                           agg1, wself2, bias2, agg2, nNodes);
        hipLaunchKernelGGL(k_edgemm2, dim3(eb), dim3(256), 0, stream,
                           agg1, src, order, offs, W2f, dpos, msg);
        hipLaunchKernelGGL(k_seg2, dim3(1024), dim3(256), 0, stream,
                           msg, nodeoff, agg2, nNodes);
    } else {
        hipLaunchKernelGGL(k_edgemm1_at, dim3(eb), dim3(256), 0, stream,
                           xbf, src, dst, order, offs, W1f, agg1);
        hipLaunchKernelGGL(k_lin2, dim3(512), dim3(256), 0, stream,
                           agg1, wself2, bias2, agg2, nNodes);
        hipLaunchKernelGGL(k_edgemm2_at, dim3(eb), dim3(256), 0, stream,
                           agg1, src, dst, order, offs, W2f, agg2);
    }
    hipLaunchKernelGGL(k_bounds, dim3(1), dim3(128), 0, stream, gid, start, nNodes);
    hipLaunchKernelGGL(k_pool, dim3(64), dim3(256), 0, stream, agg2, start, out);
}

// Round 8
// 374.116 us; speedup vs baseline: 1.5205x; 1.0285x over previous
//
#include <hip/hip_runtime.h>

// ---------------------------------------------------------------------------
// RGCN (basis decomposition, 2 layers) + mean-pool.  v8 structure:
//   xw[r] = x @ W_r for ALL nodes (dense MFMA, sequential)  [k_xw1/k_xw2]
//   edge aggregation = gather xw[src*8+et] + segment-sum over dst-CSR
//   (no per-edge GEMM, no relation sort, no atomics in hot path)
//
// ws layout (bytes):
//   W1f     us[8*4096]   @ 0            B-frags of W1 (bf16)
//   W2f     us[8*1024]   @ 65536
//   xbf     us[N*64]     @ 81920        x in bf16 (written by k_lin1x)
//   agg1    us[N*64]     @ 12881920     layer-1 agg (becomes h)
//   agg2    us[N*16]     @ 25681920     layer-2 agg
//   deg     int[N]       @ 28881920
//   nodeoff int[N+1]     @ 29281920
//   cursor  int[N]       @ 29681924
//   btot    int[512]     @ 30081924
//   boff    int[512]     @ 30083972
//   skey    int[E]       @ 30086020     src*8+et, dst-sorted
//   start   int[65]      @ 34086020
//   xw1     us[N*8*64]   @ 34086288     (102.4 MB; xw2 aliases it)
// NEED = 136,486,288 B  (harness ws proven >= 166 MB in rounds 5-7)
// ---------------------------------------------------------------------------

typedef __attribute__((ext_vector_type(8))) short bf16x8;
typedef __attribute__((ext_vector_type(4))) float f32x4;

__device__ __forceinline__ unsigned short f2bf(float f) {
    unsigned u = __float_as_uint(f);
    unsigned r = u + 0x7FFFu + ((u >> 16) & 1u);   // RNE
    return (unsigned short)(r >> 16);
}

__device__ __forceinline__ float bf2f(unsigned short u) {
    return __uint_as_float(((unsigned)u) << 16);
}

__device__ __forceinline__ float bcast(float v, int l) {
    return __uint_as_float(__builtin_amdgcn_readlane(__float_as_uint(v), l));
}

// ---- weights in B-fragment order (16x16x32 bf16): lane l holds
// B[k = kt*32+(l>>4)*8+j][n = nt*16+(l&15)], j=0..7
__global__ __launch_bounds__(256) void k_weights(
    const float* __restrict__ bases1, const float* __restrict__ coeff1,
    const float* __restrict__ bases2, const float* __restrict__ coeff2,
    unsigned short* __restrict__ W1f, unsigned short* __restrict__ W2f) {
    int r = blockIdx.x;
    int tid = threadIdx.x;
    float c1[8], c2[8];
#pragma unroll
    for (int b = 0; b < 8; ++b) { c1[b] = coeff1[r * 8 + b]; c2[b] = coeff2[r * 8 + b]; }
    for (int idx = tid; idx < 4096; idx += 256) {
        int j = idx & 7, lane = (idx >> 3) & 63, nt = (idx >> 9) & 3, kt = idx >> 11;
        int i = kt * 32 + ((lane >> 4) << 3) + j;
        int jo = nt * 16 + (lane & 15);
        float s = 0.f;
#pragma unroll
        for (int b = 0; b < 8; ++b) s = fmaf(c1[b], bases1[b * 4096 + i * 64 + jo], s);
        W1f[r * 4096 + idx] = f2bf(s);
    }
    for (int idx = tid; idx < 1024; idx += 256) {
        int j = idx & 7, lane = (idx >> 3) & 63, kt = idx >> 9;
        int i = kt * 32 + ((lane >> 4) << 3) + j;
        int jo = lane & 15;
        float s = 0.f;
#pragma unroll
        for (int b = 0; b < 8; ++b) s = fmaf(c2[b], bases2[b * 1024 + i * 16 + jo], s);
        W2f[r * 1024 + idx] = f2bf(s);
    }
}

// ---- self-loop layer1 + x->bf16 cast fused:
// agg1 = bf16(x @ wself1 + bias1);  xbf = bf16(x)
__global__ __launch_bounds__(256) void k_lin1x(
    const float* __restrict__ x, const float* __restrict__ wself,
    const float* __restrict__ bias, unsigned short* __restrict__ agg,
    unsigned short* __restrict__ xbf, int nNodes) {
    int lane = threadIdx.x & 63;
    int gw = (int)((blockIdx.x * blockDim.x + threadIdx.x) >> 6);
    int nW = (int)((gridDim.x * blockDim.x) >> 6);
    float w[64];
#pragma unroll
    for (int i = 0; i < 64; ++i) w[i] = wself[i * 64 + lane];
    float bj = bias[lane];
    for (int n = gw; n < nNodes; n += nW) {
        float xv = x[(size_t)n * 64 + lane];
        xbf[(size_t)n * 64 + lane] = f2bf(xv);
        float a0 = 0.f, a1 = 0.f, a2 = 0.f, a3 = 0.f;
#pragma unroll
        for (int i = 0; i < 64; i += 4) {
            a0 = fmaf(bcast(xv, i + 0), w[i + 0], a0);
            a1 = fmaf(bcast(xv, i + 1), w[i + 1], a1);
            a2 = fmaf(bcast(xv, i + 2), w[i + 2], a2);
            a3 = fmaf(bcast(xv, i + 3), w[i + 3], a3);
        }
        agg[(size_t)n * 64 + lane] = f2bf(bj + ((a0 + a1) + (a2 + a3)));
    }
}

// ---- dst counting sort: deg histogram -> block scan -> rank+pack
__global__ __launch_bounds__(256) void k_zero(int* __restrict__ p, int n) {
    int i = blockIdx.x * blockDim.x + threadIdx.x;
    if (i < n) p[i] = 0;
}

__global__ __launch_bounds__(256) void k_histdst(
    const int* __restrict__ dst, int* __restrict__ deg, int nE) {
    int stride = gridDim.x * blockDim.x;
    for (int e = blockIdx.x * blockDim.x + threadIdx.x; e < nE; e += stride)
        atomicAdd(&deg[dst[e]], 1);
}

__global__ __launch_bounds__(256) void k_scanblk(
    const int* __restrict__ deg, int* __restrict__ nodeoff,
    int* __restrict__ btot, int nNodes) {
    __shared__ int sm[256];
    int tid = threadIdx.x;
    int n = blockIdx.x * 256 + tid;
    int d = (n < nNodes) ? deg[n] : 0;
    sm[tid] = d;
    __syncthreads();
#pragma unroll
    for (int off = 1; off < 256; off <<= 1) {
        int v = (tid >= off) ? sm[tid - off] : 0;
        __syncthreads();
        sm[tid] += v;
        __syncthreads();
    }
    if (n < nNodes) nodeoff[n] = sm[tid] - d;       // exclusive within block
    if (tid == 255) btot[blockIdx.x] = sm[255];
}

__global__ void k_scantop(const int* __restrict__ btot, int* __restrict__ boff, int nB) {
    __shared__ int sm[512];
    int t = threadIdx.x;
    int d = (t < nB) ? btot[t] : 0;
    sm[t] = d;
    __syncthreads();
#pragma unroll
    for (int off = 1; off < 512; off <<= 1) {
        int v = (t >= off) ? sm[t - off] : 0;
        __syncthreads();
        sm[t] += v;
        __syncthreads();
    }
    if (t < nB) boff[t] = sm[t] - d;                // exclusive
}

__global__ __launch_bounds__(256) void k_scanadd(
    int* __restrict__ nodeoff, const int* __restrict__ boff,
    int* __restrict__ cursor, int nNodes, int nE) {
    int n = blockIdx.x * 256 + threadIdx.x;
    if (n < nNodes) {
        int v = nodeoff[n] + boff[n >> 8];
        nodeoff[n] = v;
        cursor[n] = v;
    } else if (n == nNodes) {
        nodeoff[n] = nE;
    }
}

// rank by dst + pack gather key (src*8+et) in one pass
__global__ __launch_bounds__(256) void k_rankpack(
    const int* __restrict__ dst, const int* __restrict__ src,
    const int* __restrict__ et, int* __restrict__ cursor,
    int* __restrict__ skey, int nE) {
    int stride = gridDim.x * blockDim.x;
    for (int e = blockIdx.x * blockDim.x + threadIdx.x; e < nE; e += stride) {
        int p = atomicAdd(&cursor[dst[e]], 1);
        skey[p] = src[e] * 8 + et[e];
    }
}

// ---- xw1[(n*8+r)*64] = bf16( x[n] @ W_r )  for all n, r  (dense MFMA)
__global__ __launch_bounds__(256) void k_xw1(
    const unsigned short* __restrict__ xbf,
    const unsigned short* __restrict__ W1f,
    unsigned short* __restrict__ xw1, int nNodes) {
    __shared__ unsigned lds[4][16 * 36];
    int lane = threadIdx.x & 63;
    int wid = (int)(threadIdx.x >> 6);
    int tile = blockIdx.x * 4 + wid;
    int n0 = tile * 16;
    if (n0 >= nNodes) return;
    int sA = n0 + (lane & 15);
    if (sA >= nNodes) sA = nNodes - 1;
    const unsigned short* xrow = xbf + (size_t)sA * 64 + ((lane >> 4) << 3);
    bf16x8 a[2];
    a[0] = *(const bf16x8*)(xrow);
    a[1] = *(const bf16x8*)(xrow + 32);
    unsigned* L = lds[wid];
    const int even = !(lane & 1);
    const int cpair = (lane & 14) >> 1;
    int row2 = lane >> 2, ch = lane & 3;
    int nOut = n0 + row2;
    for (int r = 0; r < 8; ++r) {
        const unsigned short* Wf = W1f + r * 4096;
        f32x4 z = {0.f, 0.f, 0.f, 0.f};
        f32x4 acc[4] = {z, z, z, z};
#pragma unroll
        for (int kt = 0; kt < 2; ++kt)
#pragma unroll
            for (int nt = 0; nt < 4; ++nt) {
                bf16x8 b = *(const bf16x8*)(Wf + (kt * 4 + nt) * 512 + lane * 8);
                acc[nt] = __builtin_amdgcn_mfma_f32_16x16x32_bf16(a[kt], b, acc[nt], 0, 0, 0);
            }
#pragma unroll
        for (int reg = 0; reg < 4; ++reg) {
            int row = ((lane >> 4) << 2) + reg;
#pragma unroll
            for (int nt = 0; nt < 4; ++nt) {
                float mine = acc[nt][reg];
                float oth = __shfl_xor(mine, 1, 64);
                unsigned pk = even ? ((unsigned)f2bf(mine) | ((unsigned)f2bf(oth) << 16))
                                   : ((unsigned)f2bf(oth) | ((unsigned)f2bf(mine) << 16));
                if (even ? (nt < 2) : (nt >= 2)) L[row * 36 + cpair + nt * 8] = pk;
            }
        }
        // same-wave LDS RAW; DS ops execute in order per wave
        if (nOut < nNodes) {
            uint4 v0 = *(uint4*)&L[row2 * 36 + ch * 4];
            uint4 v1 = *(uint4*)&L[row2 * 36 + 16 + ch * 4];
            uint4* mp = (uint4*)(xw1 + ((size_t)nOut * 8 + r) * 64);
            mp[ch] = v0;
            mp[4 + ch] = v1;
        }
    }
}

// ---- fused gather + segment sum, layer1 (16-lane group/node, uint2/lane)
__global__ __launch_bounds__(256) void k_seg1f(
    const unsigned short* __restrict__ xw1, const int* __restrict__ skey,
    const int* __restrict__ nodeoff, unsigned short* __restrict__ agg1,
    int nNodes) {
    int gl = threadIdx.x & 15;                 // 4 cols per lane
    int grp = (int)((blockIdx.x * blockDim.x + threadIdx.x) >> 4);
    int nG = (int)((gridDim.x * blockDim.x) >> 4);
    for (int n = grp; n < nNodes; n += nG) {
        int s0 = nodeoff[n], s1 = nodeoff[n + 1];
        uint2 v = *(const uint2*)(agg1 + (size_t)n * 64 + gl * 4);
        float a0 = bf2f((unsigned short)v.x), a1 = bf2f((unsigned short)(v.x >> 16));
        float a2 = bf2f((unsigned short)v.y), a3 = bf2f((unsigned short)(v.y >> 16));
        for (int i = s0; i < s1; ++i) {
            int key = skey[i];
            uint2 m = *(const uint2*)(xw1 + (size_t)key * 64 + gl * 4);
            a0 += bf2f((unsigned short)m.x); a1 += bf2f((unsigned short)(m.x >> 16));
            a2 += bf2f((unsigned short)m.y); a3 += bf2f((unsigned short)(m.y >> 16));
        }
        uint2 p;
        p.x = (unsigned)f2bf(a0) | ((unsigned)f2bf(a1) << 16);
        p.y = (unsigned)f2bf(a2) | ((unsigned)f2bf(a3) << 16);
        *(uint2*)(agg1 + (size_t)n * 64 + gl * 4) = p;
    }
}

// ---- relu (in-place) + self-loop layer2 -> agg2 init
__global__ __launch_bounds__(256) void k_lin2(
    unsigned short* __restrict__ agg1, const float* __restrict__ wself,
    const float* __restrict__ bias, unsigned short* __restrict__ agg2, int nNodes) {
    int lane = threadIdx.x & 63;
    int j = lane & 15;
    int gw = (int)((blockIdx.x * blockDim.x + threadIdx.x) >> 6);
    int nW = (int)((gridDim.x * blockDim.x) >> 6);
    float w[64];
#pragma unroll
    for (int i = 0; i < 64; ++i) w[i] = wself[i * 16 + j];
    float bj = bias[j];
    for (int n = gw; n < nNodes; n += nW) {
        unsigned short raw = agg1[(size_t)n * 64 + lane];
        unsigned short rbf = (raw & 0x8000u) ? (unsigned short)0 : raw;
        agg1[(size_t)n * 64 + lane] = rbf;          // h in place
        float hv = bf2f(rbf);
        float a0 = 0.f, a1 = 0.f, a2 = 0.f, a3 = 0.f;
#pragma unroll
        for (int i = 0; i < 64; i += 4) {
            a0 = fmaf(bcast(hv, i + 0), w[i + 0], a0);
            a1 = fmaf(bcast(hv, i + 1), w[i + 1], a1);
            a2 = fmaf(bcast(hv, i + 2), w[i + 2], a2);
            a3 = fmaf(bcast(hv, i + 3), w[i + 3], a3);
        }
        if (lane < 16) agg2[(size_t)n * 16 + lane] = f2bf(bj + ((a0 + a1) + (a2 + a3)));
    }
}

// ---- xw2[(n*8+r)*16] = bf16( h[n] @ W2_r )  for all n, r
__global__ __launch_bounds__(256) void k_xw2(
    const unsigned short* __restrict__ h,
    const unsigned short* __restrict__ W2f,
    unsigned short* __restrict__ xw2, int nNodes) {
    __shared__ unsigned lds[4][16 * 12];
    int lane = threadIdx.x & 63;
    int wid = (int)(threadIdx.x >> 6);
    int tile = blockIdx.x * 4 + wid;
    int n0 = tile * 16;
    if (n0 >= nNodes) return;
    int sA = n0 + (lane & 15);
    if (sA >= nNodes) sA = nNodes - 1;
    const unsigned short* hrow = h + (size_t)sA * 64 + ((lane >> 4) << 3);
    bf16x8 a[2];
    a[0] = *(const bf16x8*)(hrow);
    a[1] = *(const bf16x8*)(hrow + 32);
    unsigned* L = lds[wid];
    const int even = !(lane & 1);
    const int cpair = (lane & 14) >> 1;
    int row2 = lane >> 1, ch = lane & 1;
    int nOut = n0 + row2;
    for (int r = 0; r < 8; ++r) {
        const unsigned short* Wf = W2f + r * 1024;
        bf16x8 b0 = *(const bf16x8*)(Wf + lane * 8);
        bf16x8 b1 = *(const bf16x8*)(Wf + 512 + lane * 8);
        f32x4 acc = {0.f, 0.f, 0.f, 0.f};
        acc = __builtin_amdgcn_mfma_f32_16x16x32_bf16(a[0], b0, acc, 0, 0, 0);
        acc = __builtin_amdgcn_mfma_f32_16x16x32_bf16(a[1], b1, acc, 0, 0, 0);
#pragma unroll
        for (int reg = 0; reg < 4; ++reg) {
            int row = ((lane >> 4) << 2) + reg;
            float mine = acc[reg];
            float oth = __shfl_xor(mine, 1, 64);
            unsigned pk = even ? ((unsigned)f2bf(mine) | ((unsigned)f2bf(oth) << 16))
                               : ((unsigned)f2bf(oth) | ((unsigned)f2bf(mine) << 16));
            if (even ? (reg < 2) : (reg >= 2)) L[row * 12 + cpair] = pk;
        }
        if (lane < 32 && nOut < nNodes) {
            uint4 v = *(uint4*)&L[row2 * 12 + ch * 4];
            ((uint4*)(xw2 + ((size_t)nOut * 8 + r) * 16))[ch] = v;
        }
    }
}

// ---- fused gather + segment sum, layer2 (4-lane group/node, uint2/lane)
__global__ __launch_bounds__(256) void k_seg2f(
    const unsigned short* __restrict__ xw2, const int* __restrict__ skey,
    const int* __restrict__ nodeoff, unsigned short* __restrict__ agg2,
    int nNodes) {
    int gl = threadIdx.x & 3;                  // 4 cols per lane
    int grp = (int)((blockIdx.x * blockDim.x + threadIdx.x) >> 2);
    int nG = (int)((gridDim.x * blockDim.x) >> 2);
    for (int n = grp; n < nNodes; n += nG) {
        int s0 = nodeoff[n], s1 = nodeoff[n + 1];
        uint2 v = *(const uint2*)(agg2 + (size_t)n * 16 + gl * 4);
        float a0 = bf2f((unsigned short)v.x), a1 = bf2f((unsigned short)(v.x >> 16));
        float a2 = bf2f((unsigned short)v.y), a3 = bf2f((unsigned short)(v.y >> 16));
        for (int i = s0; i < s1; ++i) {
            int key = skey[i];
            uint2 m = *(const uint2*)(xw2 + (size_t)key * 16 + gl * 4);
            a0 += bf2f((unsigned short)m.x); a1 += bf2f((unsigned short)(m.x >> 16));
            a2 += bf2f((unsigned short)m.y); a3 += bf2f((unsigned short)(m.y >> 16));
        }
        uint2 p;
        p.x = (unsigned)f2bf(a0) | ((unsigned)f2bf(a1) << 16);
        p.y = (unsigned)f2bf(a2) | ((unsigned)f2bf(a3) << 16);
        *(uint2*)(agg2 + (size_t)n * 16 + gl * 4) = p;
    }
}

__global__ void k_bounds(const int* __restrict__ gid, int* __restrict__ start, int nNodes) {
    int t = blockIdx.x * blockDim.x + threadIdx.x;
    if (t > 64) return;
    int lo = 0, hi = nNodes;
    while (lo < hi) {
        int mid = (lo + hi) >> 1;
        if (gid[mid] < t) lo = mid + 1; else hi = mid;
    }
    start[t] = lo;
}

__global__ __launch_bounds__(256) void k_pool(
    const unsigned short* __restrict__ agg2, const int* __restrict__ start,
    float* __restrict__ out) {
    __shared__ float sm[256];
    int g = blockIdx.x;
    int t = threadIdx.x;
    int c = t & 15, idx = t >> 4;
    int s0 = start[g], s1 = start[g + 1];
    float acc = 0.f;
    for (int n = s0 + idx; n < s1; n += 16) acc += fmaxf(bf2f(agg2[(size_t)n * 16 + c]), 0.f);
    sm[t] = acc;
    __syncthreads();
#pragma unroll
    for (int off = 128; off >= 16; off >>= 1) {
        if (t < off) sm[t] += sm[t + off];
        __syncthreads();
    }
    if (t < 16) {
        float cnt = (float)(s1 - s0);
        out[g * 16 + t] = sm[t] / fmaxf(cnt, 1.f);
    }
}

extern "C" void kernel_launch(void* const* d_in, const int* in_sizes, int n_in,
                              void* d_out, int out_size, void* d_ws, size_t ws_size,
                              hipStream_t stream) {
    const float* x      = (const float*)d_in[0];
    const int*   src    = (const int*)d_in[1];
    const int*   dst    = (const int*)d_in[2];
    const int*   et     = (const int*)d_in[3];
    const int*   gid    = (const int*)d_in[4];
    const float* bases1 = (const float*)d_in[5];
    const float* coeff1 = (const float*)d_in[6];
    const float* wself1 = (const float*)d_in[7];
    const float* bias1  = (const float*)d_in[8];
    const float* bases2 = (const float*)d_in[9];
    const float* coeff2 = (const float*)d_in[10];
    const float* wself2 = (const float*)d_in[11];
    const float* bias2  = (const float*)d_in[12];
    float* out = (float*)d_out;

    int nNodes = in_sizes[0] / 64;
    int nE = in_sizes[1];

    char* ws = (char*)d_ws;
    unsigned short* W1f  = (unsigned short*)(ws);
    unsigned short* W2f  = (unsigned short*)(ws + 65536);
    unsigned short* xbf  = (unsigned short*)(ws + 81920);
    unsigned short* agg1 = (unsigned short*)(ws + 12881920);
    unsigned short* agg2 = (unsigned short*)(ws + 25681920);
    int*   deg     = (int*)(ws + 28881920);
    int*   nodeoff = (int*)(ws + 29281920);
    int*   cursor  = (int*)(ws + 29681924);
    int*   btot    = (int*)(ws + 30081924);
    int*   boff    = (int*)(ws + 30083972);
    int*   skey    = (int*)(ws + 30086020);
    int*   start   = (int*)(ws + 34086020);
    unsigned short* xw1 = (unsigned short*)(ws + 34086288);
    unsigned short* xw2 = xw1;   // layer-2 reuses xw1 space

    int nB = (nNodes + 255) / 256;
    int tiles = (nNodes + 15) / 16;
    int xwb = (tiles + 3) / 4;

    hipLaunchKernelGGL(k_weights, dim3(8), dim3(256), 0, stream,
                       bases1, coeff1, bases2, coeff2, W1f, W2f);
    hipLaunchKernelGGL(k_lin1x, dim3(512), dim3(256), 0, stream,
                       x, wself1, bias1, agg1, xbf, nNodes);
    hipLaunchKernelGGL(k_zero, dim3(nB), dim3(256), 0, stream, deg, nNodes);
    hipLaunchKernelGGL(k_histdst, dim3(1024), dim3(256), 0, stream, dst, deg, nE);
    hipLaunchKernelGGL(k_scanblk, dim3(nB), dim3(256), 0, stream,
                       deg, nodeoff, btot, nNodes);
    hipLaunchKernelGGL(k_scantop, dim3(1), dim3(512), 0, stream, btot, boff, nB);
    hipLaunchKernelGGL(k_scanadd, dim3(nB + 1), dim3(256), 0, stream,
                       nodeoff, boff, cursor, nNodes, nE);
    hipLaunchKernelGGL(k_rankpack, dim3(1024), dim3(256), 0, stream,
                       dst, src, et, cursor, skey, nE);
    hipLaunchKernelGGL(k_xw1, dim3(xwb), dim3(256), 0, stream,
                       xbf, W1f, xw1, nNodes);
    hipLaunchKernelGGL(k_seg1f, dim3(2048), dim3(256), 0, stream,
                       xw1, skey, nodeoff, agg1, nNodes);
    hipLaunchKernelGGL(k_lin2, dim3(512), dim3(256), 0, stream,
                       agg1, wself2, bias2, agg2, nNodes);
    hipLaunchKernelGGL(k_xw2, dim3(xwb), dim3(256), 0, stream,
                       agg1, W2f, xw2, nNodes);
    hipLaunchKernelGGL(k_seg2f, dim3(1024), dim3(256), 0, stream,
                       xw2, skey, nodeoff, agg2, nNodes);
    hipLaunchKernelGGL(k_bounds, dim3(1), dim3(128), 0, stream, gid, start, nNodes);
    hipLaunchKernelGGL(k_pool, dim3(64), dim3(256), 0, stream, agg2, start, out);
}